// Round 8
// baseline (298.596 us; speedup 1.0000x reference)
//
#include <hip/hip_runtime.h>
#include <hip/hip_bf16.h>

typedef __attribute__((ext_vector_type(4))) float f32x4;

// ---------------- workspace layout (fp32 elements) ----------------
constexpr int WSF_Q     = 0;        // 512    attention query (conv3 out)
constexpr int WSF_ADEN  = 512;      // 64     per-chunk exp-sum
constexpr int WSF_BAR   = 576;      // 64 ints: slots 0-2 = gru4 barriers, [48]=vocab ctr, [49]=vocab flag
constexpr int WSF_LSE   = 656;      // 1      logsumexp (own cache line)
constexpr int WSF_APART = 1024;     // 64*1024 per-chunk PV partials (unnormalized)
constexpr int WSF_XT    = 66560;    // 5*512  xt chain
constexpr int WSF_PM    = 119424;   // 786    per-block max
constexpr int WSF_PS    = 120320;   // 786    per-block sum-exp
constexpr int NVOCAB    = 50257;
constexpr int NBLK_V    = 786;      // ceil(50257/64)

__device__ __forceinline__ float wave_rsum(float v) {
#pragma unroll
    for (int o = 32; o > 0; o >>= 1) v += __shfl_down(v, o);
    return v; // lane 0 holds sum
}
__device__ __forceinline__ float sigm(float x) { return 1.0f / (1.0f + __expf(-x)); }

// Global barrier for nblk co-resident blocks (grid <= #CUs => all resident).
// Slot ints zeroed by k_post earlier in the stream.  Semantics proven R7.
__device__ __forceinline__ void gbar(float* wsf, int slot, int nblk) {
    int* bar = reinterpret_cast<int*>(wsf + WSF_BAR) + slot * 16;
    __threadfence();
    __syncthreads();
    if (threadIdx.x == 0) {
        int v = __hip_atomic_fetch_add(bar, 1, __ATOMIC_ACQ_REL, __HIP_MEMORY_SCOPE_AGENT);
        if (v == nblk - 1) {
            __hip_atomic_store(bar + 1, 1, __ATOMIC_RELEASE, __HIP_MEMORY_SCOPE_AGENT);
        } else {
            while (__hip_atomic_load(bar + 1, __ATOMIC_ACQUIRE, __HIP_MEMORY_SCOPE_AGENT) == 0)
                __builtin_amdgcn_s_sleep(1);
        }
    }
    __syncthreads();
    __threadfence();
}

// =====================================================================
// K1: pre-attention conv stack.  1 block x 512 threads (thread = position)
// =====================================================================
__global__ __launch_bounds__(512) void k_pre(
    const float* __restrict__ emb, const int* __restrict__ xidx,
    const float* __restrict__ hstate,
    const float* __restrict__ w1, const float* __restrict__ b1,
    const float* __restrict__ w2, const float* __restrict__ b2,
    const float* __restrict__ w3, const float* __restrict__ b3,
    const float* __restrict__ g1, const float* __restrict__ bb1,
    const float* __restrict__ g2, const float* __restrict__ bb2,
    const float* __restrict__ g3, const float* __restrict__ bb3,
    float* __restrict__ ws)
{
    constexpr int W1 = 0, B1 = 480, G1 = 512, BB1 = 544;
    constexpr int W2 = 576, B2 = 1056, G2 = 1061, BB2 = 1066;
    constexpr int W3 = 1071, B3 = 1086, G3 = 1087, BB3 = 1088, NW = 1089;
    __shared__ float s_w[NW];
    __shared__ float s_pre[5][512];
    __shared__ float s_y[32][512];
    __shared__ float s_stat[32][2];
    const int tid = threadIdx.x, lane = tid & 63, wid = tid >> 6, l = tid;

    if (tid < 480) s_w[W1 + tid] = w1[tid];
    if (tid < 32) { s_w[B1 + tid] = b1[tid]; s_w[G1 + tid] = g1[tid]; s_w[BB1 + tid] = bb1[tid]; }
    if (tid < 480) s_w[W2 + tid] = w2[tid];
    if (tid < 5) { s_w[B2 + tid] = b2[tid]; s_w[G2 + tid] = g2[tid]; s_w[BB2 + tid] = bb2[tid]; }
    if (tid < 15) s_w[W3 + tid] = w3[tid];
    if (tid == 0) { s_w[B3] = b3[0]; s_w[G3] = g3[0]; s_w[BB3] = bb3[0]; }

    const int x = xidx[0];
#pragma unroll
    for (int c = 0; c < 4; ++c) s_pre[c][l] = hstate[c * 512 + l];
    s_pre[4][l] = emb[(size_t)x * 512 + l];
    __syncthreads();

    // ---- conv1 (5->32) ----
    float px[5][3];
#pragma unroll
    for (int ic = 0; ic < 5; ++ic) {
        px[ic][0] = (l > 0)   ? s_pre[ic][l-1] : 0.f;
        px[ic][1] =             s_pre[ic][l];
        px[ic][2] = (l < 511) ? s_pre[ic][l+1] : 0.f;
    }
#pragma unroll 4
    for (int oc = 0; oc < 32; ++oc) {
        float a = s_w[B1 + oc];
#pragma unroll
        for (int ic = 0; ic < 5; ++ic)
#pragma unroll
            for (int k = 0; k < 3; ++k)
                a += s_w[W1 + oc*15 + ic*3 + k] * px[ic][k];
        s_y[oc][l] = a;
    }
    __syncthreads();
#pragma unroll
    for (int t = 0; t < 4; ++t) {
        const int oc = wid * 4 + t;
        float s = 0.f, s2 = 0.f;
#pragma unroll
        for (int j = 0; j < 8; ++j) { float v = s_y[oc][lane + j*64]; s += v; s2 += v*v; }
        s = wave_rsum(s); s2 = wave_rsum(s2);
        if (lane == 0) { float m = s/512.f, var = s2/512.f - m*m; s_stat[oc][0] = m; s_stat[oc][1] = rsqrtf(var + 1e-5f); }
    }
    __syncthreads();
#pragma unroll 4
    for (int oc = 0; oc < 32; ++oc)
        s_y[oc][l] = fmaxf((s_y[oc][l] - s_stat[oc][0]) * s_stat[oc][1] * s_w[G1+oc] + s_w[BB1+oc], 0.f);
    __syncthreads();

    // ---- conv2 (32->5) + residual ----
    float y2[5];
#pragma unroll
    for (int oc = 0; oc < 5; ++oc) y2[oc] = s_w[B2 + oc];
#pragma unroll 2
    for (int ic = 0; ic < 32; ++ic) {
        float c0 = (l > 0)   ? s_y[ic][l-1] : 0.f;
        float c1 =             s_y[ic][l];
        float c2 = (l < 511) ? s_y[ic][l+1] : 0.f;
#pragma unroll
        for (int oc = 0; oc < 5; ++oc) {
            const int base = W2 + (oc*32 + ic)*3;
            y2[oc] += s_w[base]*c0 + s_w[base+1]*c1 + s_w[base+2]*c2;
        }
    }
#pragma unroll
    for (int oc = 0; oc < 5; ++oc) y2[oc] += s_pre[oc][l];
    __syncthreads();
#pragma unroll
    for (int oc = 0; oc < 5; ++oc) s_y[oc][l] = y2[oc];
    __syncthreads();
    if (wid < 5) {
        const int oc = wid;
        float s = 0.f, s2 = 0.f;
#pragma unroll
        for (int j = 0; j < 8; ++j) { float v = s_y[oc][lane + j*64]; s += v; s2 += v*v; }
        s = wave_rsum(s); s2 = wave_rsum(s2);
        if (lane == 0) { float m = s/512.f, var = s2/512.f - m*m; s_stat[oc][0] = m; s_stat[oc][1] = rsqrtf(var + 1e-5f); }
    }
    __syncthreads();
#pragma unroll
    for (int oc = 0; oc < 5; ++oc)
        s_pre[oc][l] = fmaxf((y2[oc] - s_stat[oc][0]) * s_stat[oc][1] * s_w[G2+oc] + s_w[BB2+oc], 0.f);
    __syncthreads();

    // ---- conv3 (5->1) ----
    float a3 = s_w[B3];
#pragma unroll
    for (int ic = 0; ic < 5; ++ic) {
        float c0 = (l > 0)   ? s_pre[ic][l-1] : 0.f;
        float c1 =             s_pre[ic][l];
        float c2 = (l < 511) ? s_pre[ic][l+1] : 0.f;
        a3 += s_w[W3+ic*3]*c0 + s_w[W3+ic*3+1]*c1 + s_w[W3+ic*3+2]*c2;
    }
    s_y[0][l] = a3;
    __syncthreads();
    if (wid == 0) {
        float s = 0.f, s2 = 0.f;
#pragma unroll
        for (int j = 0; j < 8; ++j) { float v = s_y[0][lane + j*64]; s += v; s2 += v*v; }
        s = wave_rsum(s); s2 = wave_rsum(s2);
        if (lane == 0) { float m = s/512.f, var = s2/512.f - m*m; s_stat[0][0] = m; s_stat[0][1] = rsqrtf(var + 1e-5f); }
    }
    __syncthreads();
    ws[WSF_Q + l] = fmaxf((a3 - s_stat[0][0]) * s_stat[0][1] * s_w[G3] + s_w[BB3], 0.f);
}

// =====================================================================
// K2: fused attention.  64 blocks x 256.  (R6-proven)
// =====================================================================
__global__ __launch_bounds__(256) void k_att(
    const float* __restrict__ attw, const float* __restrict__ attb,
    const float* __restrict__ enc, float* __restrict__ ws)
{
    __shared__ float s_e[32];
    __shared__ float s_d[4];
    const int tid = threadIdx.x, lane = tid & 63, wid = tid >> 6;
    const int jc = blockIdx.x;

    float q0[4], q1[4];
#pragma unroll
    for (int j = 0; j < 4; ++j) {
        q0[j] = ws[WSF_Q + lane*4 + j];
        q1[j] = ws[WSF_Q + 256 + lane*4 + j];
    }
    float dpart = 0.f;
#pragma unroll 4
    for (int r = 0; r < 8; ++r) {
        const int row = jc * 32 + wid * 8 + r;
        f32x4 w0 = *(const f32x4*)(attw + (size_t)row*512 + lane*4);
        f32x4 w1 = *(const f32x4*)(attw + (size_t)row*512 + 256 + lane*4);
        float a = 0.f;
#pragma unroll
        for (int j = 0; j < 4; ++j) a += w0[j]*q0[j] + w1[j]*q1[j];
        a = wave_rsum(a);
        if (lane == 0) {
            float e = __expf(a + attb[row]);   // |logit| << 80: exp-safe (R5/R6)
            s_e[wid*8 + r] = e;
            dpart += e;
        }
    }
    if (lane == 0) s_d[wid] = dpart;
    __syncthreads();
    if (tid == 0) ws[WSF_ADEN + jc] = s_d[0] + s_d[1] + s_d[2] + s_d[3];

    const int col = tid * 4;
    const float* ep = enc + (size_t)(jc * 32) * 1024 + col;
    f32x4 acc = {0.f, 0.f, 0.f, 0.f};
#pragma unroll 8
    for (int jj = 0; jj < 32; ++jj) {
        f32x4 v = *(const f32x4*)(ep + (size_t)jj * 1024);
        acc += s_e[jj] * v;
    }
    *(f32x4*)(ws + WSF_APART + jc * 1024 + col) = acc;
}

// =====================================================================
// K3: post-attention conv stack.  1 block x 512 threads.
// Zeroes all barrier/counter slots for k_gru4 and k_vocab_out.
// =====================================================================
__global__ __launch_bounds__(512) void k_post(
    const float* __restrict__ emb, const int* __restrict__ xidx,
    const float* __restrict__ w4, const float* __restrict__ b4,
    const float* __restrict__ w5, const float* __restrict__ b5,
    const float* __restrict__ w6, const float* __restrict__ b6,
    const float* __restrict__ g4, const float* __restrict__ bb4,
    const float* __restrict__ g5, const float* __restrict__ bb5,
    const float* __restrict__ g6, const float* __restrict__ bb6,
    float* __restrict__ ws)
{
    constexpr int W4 = 0, B4 = 288, G4 = 320, BB4 = 352;
    constexpr int W5 = 384, B5 = 672, G5 = 675, BB5 = 678;
    constexpr int W6 = 681, B6 = 690, G6 = 691, BB6 = 692, NW = 693;
    __shared__ float s_w[NW];
    __shared__ float s_com[3][512];
    __shared__ float s_y[32][512];
    __shared__ float s_stat[32][2];
    const int tid = threadIdx.x, lane = tid & 63, wid = tid >> 6, l = tid;

    if (tid < 64) reinterpret_cast<int*>(ws + WSF_BAR)[tid] = 0;   // barrier init

    if (tid < 288) s_w[W4 + tid] = w4[tid];
    if (tid < 32) { s_w[B4 + tid] = b4[tid]; s_w[G4 + tid] = g4[tid]; s_w[BB4 + tid] = bb4[tid]; }
    if (tid < 288) s_w[W5 + tid] = w5[tid];
    if (tid < 3) { s_w[B5 + tid] = b5[tid]; s_w[G5 + tid] = g5[tid]; s_w[BB5 + tid] = bb5[tid]; }
    if (tid < 9) s_w[W6 + tid] = w6[tid];
    if (tid == 0) { s_w[B6] = b6[0]; s_w[G6] = g6[0]; s_w[BB6] = bb6[0]; }

    float den = 0.f;
#pragma unroll 8
    for (int i = 0; i < 64; ++i) den += ws[WSF_ADEN + i];
    const float invS = 1.0f / den;
    float a0 = 0.f, a1 = 0.f;
#pragma unroll 8
    for (int p = 0; p < 64; ++p) {
        a0 += ws[WSF_APART + p*1024 + l];
        a1 += ws[WSF_APART + p*1024 + 512 + l];
    }
    const int x = xidx[0];
    s_com[0][l] = a0 * invS;
    s_com[1][l] = a1 * invS;
    s_com[2][l] = emb[(size_t)x*512 + l];
    __syncthreads();

    // ---- conv4 (3->32) ----
    float px[3][3];
#pragma unroll
    for (int ic = 0; ic < 3; ++ic) {
        px[ic][0] = (l > 0)   ? s_com[ic][l-1] : 0.f;
        px[ic][1] =             s_com[ic][l];
        px[ic][2] = (l < 511) ? s_com[ic][l+1] : 0.f;
    }
#pragma unroll 4
    for (int oc = 0; oc < 32; ++oc) {
        float a = s_w[B4 + oc];
#pragma unroll
        for (int ic = 0; ic < 3; ++ic)
#pragma unroll
            for (int k = 0; k < 3; ++k)
                a += s_w[W4 + oc*9 + ic*3 + k] * px[ic][k];
        s_y[oc][l] = a;
    }
    __syncthreads();
#pragma unroll
    for (int t = 0; t < 4; ++t) {
        const int oc = wid * 4 + t;
        float s = 0.f, s2 = 0.f;
#pragma unroll
        for (int j = 0; j < 8; ++j) { float v = s_y[oc][lane + j*64]; s += v; s2 += v*v; }
        s = wave_rsum(s); s2 = wave_rsum(s2);
        if (lane == 0) { float m = s/512.f, var = s2/512.f - m*m; s_stat[oc][0] = m; s_stat[oc][1] = rsqrtf(var + 1e-5f); }
    }
    __syncthreads();
#pragma unroll 4
    for (int oc = 0; oc < 32; ++oc)
        s_y[oc][l] = fmaxf((s_y[oc][l] - s_stat[oc][0]) * s_stat[oc][1] * s_w[G4+oc] + s_w[BB4+oc], 0.f);
    __syncthreads();

    // ---- conv5 (32->3) + residual ----
    float y2[3];
#pragma unroll
    for (int oc = 0; oc < 3; ++oc) y2[oc] = s_w[B5 + oc];
#pragma unroll 2
    for (int ic = 0; ic < 32; ++ic) {
        float c0 = (l > 0)   ? s_y[ic][l-1] : 0.f;
        float c1 =             s_y[ic][l];
        float c2 = (l < 511) ? s_y[ic][l+1] : 0.f;
#pragma unroll
        for (int oc = 0; oc < 3; ++oc) {
            const int base = W5 + (oc*32 + ic)*3;
            y2[oc] += s_w[base]*c0 + s_w[base+1]*c1 + s_w[base+2]*c2;
        }
    }
#pragma unroll
    for (int oc = 0; oc < 3; ++oc) y2[oc] += s_com[oc][l];
    __syncthreads();
#pragma unroll
    for (int oc = 0; oc < 3; ++oc) s_y[oc][l] = y2[oc];
    __syncthreads();
    if (wid < 3) {
        const int oc = wid;
        float s = 0.f, s2 = 0.f;
#pragma unroll
        for (int j = 0; j < 8; ++j) { float v = s_y[oc][lane + j*64]; s += v; s2 += v*v; }
        s = wave_rsum(s); s2 = wave_rsum(s2);
        if (lane == 0) { float m = s/512.f, var = s2/512.f - m*m; s_stat[oc][0] = m; s_stat[oc][1] = rsqrtf(var + 1e-5f); }
    }
    __syncthreads();
#pragma unroll
    for (int oc = 0; oc < 3; ++oc)
        s_com[oc][l] = fmaxf((y2[oc] - s_stat[oc][0]) * s_stat[oc][1] * s_w[G5+oc] + s_w[BB5+oc], 0.f);
    __syncthreads();

    // ---- conv6 (3->1) ----
    float a6 = s_w[B6];
#pragma unroll
    for (int ic = 0; ic < 3; ++ic) {
        float c0 = (l > 0)   ? s_com[ic][l-1] : 0.f;
        float c1 =             s_com[ic][l];
        float c2 = (l < 511) ? s_com[ic][l+1] : 0.f;
        a6 += s_w[W6+ic*3]*c0 + s_w[W6+ic*3+1]*c1 + s_w[W6+ic*3+2]*c2;
    }
    s_y[0][l] = a6;
    __syncthreads();
    if (wid == 0) {
        float s = 0.f, s2 = 0.f;
#pragma unroll
        for (int j = 0; j < 8; ++j) { float v = s_y[0][lane + j*64]; s += v; s2 += v*v; }
        s = wave_rsum(s); s2 = wave_rsum(s2);
        if (lane == 0) { float m = s/512.f, var = s2/512.f - m*m; s_stat[0][0] = m; s_stat[0][1] = rsqrtf(var + 1e-5f); }
    }
    __syncthreads();
    ws[WSF_XT + l] = fmaxf((a6 - s_stat[0][0]) * s_stat[0][1] * s_w[G6] + s_w[BB6], 0.f);
}

// =====================================================================
// K4: all 4 GRU layers, ONE PLAIN LAUNCH.  64 blocks x 256 (<= #CUs,
// all co-resident); gbar between layers (body identical to R7-proven).
// =====================================================================
__global__ __launch_bounds__(256) void k_gru4(
    const float* __restrict__ wih_, const float* __restrict__ whh_,
    const float* __restrict__ bih_, const float* __restrict__ bhh_,
    const float* __restrict__ hstate,
    float* ws, float* __restrict__ out)
{
    const int tid = threadIdx.x, lane = tid & 63, wid = tid >> 6;
    const int i0 = blockIdx.x * 8;
    __shared__ float s_g[8][6];

#pragma unroll 1
    for (int l = 0; l < 4; ++l) {
        const float* wih = wih_ + (size_t)l * 1536 * 512;
        const float* whh = whh_ + (size_t)l * 1536 * 512;
        const float* bih = bih_ + l * 1536;
        const float* bhh = bhh_ + l * 1536;
        const float* hp  = hstate + l * 512;
        const float* xt_in = ws + WSF_XT + l * 512;
        float* xt_out = ws + WSF_XT + (l + 1) * 512;

        float xq0[4], xq1[4], hq0[4], hq1[4];
#pragma unroll
        for (int j = 0; j < 4; ++j) {
            xq0[j] = xt_in[lane*4 + j];
            xq1[j] = xt_in[256 + lane*4 + j];
            hq0[j] = hp[lane*4 + j];
            hq1[j] = hp[256 + lane*4 + j];
        }
#pragma unroll
        for (int t = 0; t < 2; ++t) {
            const int ii = wid * 2 + t;
            const int i = i0 + ii;
            float a[6] = {0.f, 0.f, 0.f, 0.f, 0.f, 0.f};
#pragma unroll
            for (int g = 0; g < 3; ++g) {
                const float* wr = wih + (size_t)(i + g*512) * 512;
                f32x4 w0 = *(const f32x4*)(wr + lane*4);
                f32x4 w1 = *(const f32x4*)(wr + 256 + lane*4);
#pragma unroll
                for (int j = 0; j < 4; ++j) a[g] += w0[j]*xq0[j] + w1[j]*xq1[j];
            }
#pragma unroll
            for (int g = 0; g < 3; ++g) {
                const float* wr = whh + (size_t)(i + g*512) * 512;
                f32x4 w0 = *(const f32x4*)(wr + lane*4);
                f32x4 w1 = *(const f32x4*)(wr + 256 + lane*4);
#pragma unroll
                for (int j = 0; j < 4; ++j) a[3+g] += w0[j]*hq0[j] + w1[j]*hq1[j];
            }
#pragma unroll
            for (int g = 0; g < 6; ++g) a[g] = wave_rsum(a[g]);
            if (lane == 0) {
#pragma unroll
                for (int g = 0; g < 6; ++g) s_g[ii][g] = a[g];
            }
        }
        __syncthreads();
        if (tid < 8) {
            const int i = i0 + tid;
            float ir = s_g[tid][0] + bih[i];
            float iz = s_g[tid][1] + bih[i + 512];
            float in_ = s_g[tid][2] + bih[i + 1024];
            float hr = s_g[tid][3] + bhh[i];
            float hz = s_g[tid][4] + bhh[i + 512];
            float hn = s_g[tid][5] + bhh[i + 1024];
            float r = sigm(ir + hr);
            float z = sigm(iz + hz);
            float n = tanhf(in_ + r * hn);
            float h = (1.f - z) * n + z * hp[i];
            xt_out[i] = h;
            out[NVOCAB + l*512 + i] = h;
        }
        if (l < 3) gbar(ws, l, 64);
        else __syncthreads();
    }
}

// =====================================================================
// K5: vocab GEMV + last-block LSE + direct log-prob write.  786 x 256.
// All blocks co-resident (3.1 blocks/CU << 8 capacity).  Deterministic:
// the LSE combine runs in fixed order regardless of which block is last.
// =====================================================================
__global__ __launch_bounds__(256) void k_vocab_out(
    const float* __restrict__ low, const float* __restrict__ lob,
    float* ws, float* __restrict__ out)
{
    __shared__ float s_logit[64];
    __shared__ float smx[4], ssx[4];
    __shared__ float s_r1[256], s_r2[256];
    __shared__ int s_islast;
    __shared__ float s_lse;
    const int tid = threadIdx.x, lane = tid & 63, wid = tid >> 6;
    const int bid = blockIdx.x;
    int* bar = reinterpret_cast<int*>(ws + WSF_BAR);

    float q0[4], q1[4];
#pragma unroll
    for (int j = 0; j < 4; ++j) {
        q0[j] = ws[WSF_XT + 4*512 + lane*4 + j];
        q1[j] = ws[WSF_XT + 4*512 + 256 + lane*4 + j];
    }
    const int row0 = bid * 64 + wid * 16;
    float m = -INFINITY, s = 0.0f;
#pragma unroll 4
    for (int r = 0; r < 16; ++r) {
        const int row = row0 + r;
        if (row < NVOCAB) {
            f32x4 w0 = *(const f32x4*)(low + (size_t)row*512 + lane*4);
            f32x4 w1 = *(const f32x4*)(low + (size_t)row*512 + 256 + lane*4);
            float a = 0.f;
#pragma unroll
            for (int j = 0; j < 4; ++j) a += w0[j]*q0[j] + w1[j]*q1[j];
            a = wave_rsum(a);
            if (lane == 0) {
                float v = a + lob[row];
                s_logit[wid*16 + r] = v;
                if (v > m) { s = s * __expf(m - v) + 1.0f; m = v; }
                else       { s += __expf(v - m); }
            }
        } else if (lane == 0) {
            s_logit[wid*16 + r] = 0.f;
        }
    }
    if (lane == 0) { smx[wid] = m; ssx[wid] = s; }
    __syncthreads();
    if (tid == 0) {
        float M = -INFINITY, S = 0.0f;
#pragma unroll
        for (int w = 0; w < 4; ++w) {
            float mb = smx[w], sb = ssx[w];
            if (sb > 0.0f) {
                if (mb > M) { S = S * __expf(M - mb) + sb; M = mb; }
                else        { S += sb * __expf(mb - M); }
            }
        }
        ws[WSF_PM + bid] = M;
        ws[WSF_PS + bid] = S;
    }
    __threadfence();
    __syncthreads();
    if (tid == 0) {
        int v = __hip_atomic_fetch_add(bar + 48, 1, __ATOMIC_ACQ_REL, __HIP_MEMORY_SCOPE_AGENT);
        s_islast = (v == NBLK_V - 1) ? 1 : 0;
    }
    __syncthreads();

    if (s_islast) {
        // parallel LSE combine over all 786 (m,s) pairs, fixed order
        float M = -INFINITY, S = 0.0f;
        for (int i = tid; i < NBLK_V; i += 256) {
            float mb = ws[WSF_PM + i], sb = ws[WSF_PS + i];
            if (mb > M) { S = S * __expf(M - mb) + sb; M = mb; }
            else        { S += sb * __expf(mb - M); }
        }
        s_r1[tid] = M; s_r2[tid] = S;
        __syncthreads();
        for (int st = 128; st > 0; st >>= 1) {
            if (tid < st) {
                float mb = s_r1[tid + st], sb = s_r2[tid + st];
                if (sb > 0.0f) {
                    if (mb > s_r1[tid]) { s_r2[tid] = s_r2[tid] * __expf(s_r1[tid] - mb) + sb; s_r1[tid] = mb; }
                    else                { s_r2[tid] += sb * __expf(mb - s_r1[tid]); }
                }
            }
            __syncthreads();
        }
        if (tid == 0) {
            float lse = s_r1[0] + logf(s_r2[0]);
            s_lse = lse;
            ws[WSF_LSE] = lse;
            __threadfence();
            __hip_atomic_store(bar + 49, 1, __ATOMIC_RELEASE, __HIP_MEMORY_SCOPE_AGENT);
        }
    } else {
        if (tid == 0) {
            while (__hip_atomic_load(bar + 49, __ATOMIC_ACQUIRE, __HIP_MEMORY_SCOPE_AGENT) == 0)
                __builtin_amdgcn_s_sleep(1);
            s_lse = __hip_atomic_load(ws + WSF_LSE, __ATOMIC_RELAXED, __HIP_MEMORY_SCOPE_AGENT);
        }
    }
    __syncthreads();
    const float lse = s_lse;
    if (tid < 64) {
        const int row = bid * 64 + tid;
        if (row < NVOCAB) out[row] = s_logit[tid] - lse;
    }
}

// =====================================================================
extern "C" void kernel_launch(void* const* d_in, const int* in_sizes, int n_in,
                              void* d_out, int out_size, void* d_ws, size_t ws_size,
                              hipStream_t stream)
{
    (void)in_sizes; (void)n_in; (void)out_size; (void)ws_size;
    const float* emb     = (const float*)d_in[0];
    const float* conv1_w = (const float*)d_in[1];  const float* conv1_b = (const float*)d_in[2];
    const float* conv2_w = (const float*)d_in[3];  const float* conv2_b = (const float*)d_in[4];
    const float* conv3_w = (const float*)d_in[5];  const float* conv3_b = (const float*)d_in[6];
    const float* conv4_w = (const float*)d_in[7];  const float* conv4_b = (const float*)d_in[8];
    const float* conv5_w = (const float*)d_in[9];  const float* conv5_b = (const float*)d_in[10];
    const float* conv6_w = (const float*)d_in[11]; const float* conv6_b = (const float*)d_in[12];
    const float* bn1_g = (const float*)d_in[13];   const float* bn1_b = (const float*)d_in[14];
    const float* bn2_g = (const float*)d_in[15];   const float* bn2_b = (const float*)d_in[16];
    const float* bn3_g = (const float*)d_in[17];   const float* bn3_b = (const float*)d_in[18];
    const float* bn4_g = (const float*)d_in[19];   const float* bn4_b = (const float*)d_in[20];
    const float* bn5_g = (const float*)d_in[21];   const float* bn5_b = (const float*)d_in[22];
    const float* bn6_g = (const float*)d_in[23];   const float* bn6_b = (const float*)d_in[24];
    const float* att_w = (const float*)d_in[25];   const float* att_b = (const float*)d_in[26];
    const float* gru_wih = (const float*)d_in[27]; const float* gru_whh = (const float*)d_in[28];
    const float* gru_bih = (const float*)d_in[29]; const float* gru_bhh = (const float*)d_in[30];
    const float* lo_w = (const float*)d_in[31];    const float* lo_b = (const float*)d_in[32];
    const float* h_state = (const float*)d_in[33];
    const float* enc = (const float*)d_in[34];
    const int* x = (const int*)d_in[35];

    float* ws = (float*)d_ws;
    float* out = (float*)d_out;

    k_pre<<<1, 512, 0, stream>>>(emb, x, h_state,
        conv1_w, conv1_b, conv2_w, conv2_b, conv3_w, conv3_b,
        bn1_g, bn1_b, bn2_g, bn2_b, bn3_g, bn3_b, ws);
    k_att<<<64, 256, 0, stream>>>(att_w, att_b, enc, ws);
    k_post<<<1, 512, 0, stream>>>(emb, x,
        conv4_w, conv4_b, conv5_w, conv5_b, conv6_w, conv6_b,
        bn4_g, bn4_b, bn5_g, bn5_b, bn6_g, bn6_b, ws);
    k_gru4<<<64, 256, 0, stream>>>(gru_wih, gru_whh, gru_bih, gru_bhh, h_state, ws, out);
    k_vocab_out<<<NBLK_V, 256, 0, stream>>>(lo_w, lo_b, ws, out);
}

// Round 9
// 121.508 us; speedup vs baseline: 2.4574x; 2.4574x over previous
//
#include <hip/hip_runtime.h>
#include <hip/hip_bf16.h>

typedef __attribute__((ext_vector_type(4))) float f32x4;

// ---------------- workspace layout (fp32 elements) ----------------
constexpr int WSF_Q     = 0;        // 512    attention query (conv3 out)
constexpr int WSF_ADEN  = 512;      // 64     per-chunk exp-sum
constexpr int WSF_BAR   = 576;      // 64 ints: slots 0-2 = gru4 barriers (zeroed by k_post)
constexpr int WSF_APART = 1024;     // 64*1024 per-chunk PV partials (unnormalized)
constexpr int WSF_XT    = 66560;    // 5*512  xt chain
constexpr int WSF_LOGV  = 69120;    // 50257  vocab logits
constexpr int WSF_PM    = 119424;   // 786    per-block max
constexpr int WSF_PS    = 120320;   // 786    per-block sum-exp
constexpr int NVOCAB    = 50257;
constexpr int NBLK_V    = 786;      // ceil(50257/64)

__device__ __forceinline__ float wave_rsum(float v) {
#pragma unroll
    for (int o = 32; o > 0; o >>= 1) v += __shfl_down(v, o);
    return v; // lane 0 holds sum
}
__device__ __forceinline__ float sigm(float x) { return 1.0f / (1.0f + __expf(-x)); }

// Global barrier for nblk co-resident blocks, plain launch (grid <= #CUs).
// Proven cheap at 64 blocks with short, symmetric waits (R8).
// DO NOT use with many blocks / long asymmetric spins (R8: coherence storm).
__device__ __forceinline__ void gbar(float* wsf, int slot, int nblk) {
    int* bar = reinterpret_cast<int*>(wsf + WSF_BAR) + slot * 16;
    __threadfence();
    __syncthreads();
    if (threadIdx.x == 0) {
        int v = __hip_atomic_fetch_add(bar, 1, __ATOMIC_ACQ_REL, __HIP_MEMORY_SCOPE_AGENT);
        if (v == nblk - 1) {
            __hip_atomic_store(bar + 1, 1, __ATOMIC_RELEASE, __HIP_MEMORY_SCOPE_AGENT);
        } else {
            while (__hip_atomic_load(bar + 1, __ATOMIC_ACQUIRE, __HIP_MEMORY_SCOPE_AGENT) == 0)
                __builtin_amdgcn_s_sleep(1);
        }
    }
    __syncthreads();
    __threadfence();
}

// =====================================================================
// K1: pre-attention conv stack.  1 block x 512 threads (thread = position)
// =====================================================================
__global__ __launch_bounds__(512) void k_pre(
    const float* __restrict__ emb, const int* __restrict__ xidx,
    const float* __restrict__ hstate,
    const float* __restrict__ w1, const float* __restrict__ b1,
    const float* __restrict__ w2, const float* __restrict__ b2,
    const float* __restrict__ w3, const float* __restrict__ b3,
    const float* __restrict__ g1, const float* __restrict__ bb1,
    const float* __restrict__ g2, const float* __restrict__ bb2,
    const float* __restrict__ g3, const float* __restrict__ bb3,
    float* __restrict__ ws)
{
    constexpr int W1 = 0, B1 = 480, G1 = 512, BB1 = 544;
    constexpr int W2 = 576, B2 = 1056, G2 = 1061, BB2 = 1066;
    constexpr int W3 = 1071, B3 = 1086, G3 = 1087, BB3 = 1088, NW = 1089;
    __shared__ float s_w[NW];
    __shared__ float s_pre[5][512];
    __shared__ float s_y[32][512];
    __shared__ float s_stat[32][2];
    const int tid = threadIdx.x, lane = tid & 63, wid = tid >> 6, l = tid;

    if (tid < 480) s_w[W1 + tid] = w1[tid];
    if (tid < 32) { s_w[B1 + tid] = b1[tid]; s_w[G1 + tid] = g1[tid]; s_w[BB1 + tid] = bb1[tid]; }
    if (tid < 480) s_w[W2 + tid] = w2[tid];
    if (tid < 5) { s_w[B2 + tid] = b2[tid]; s_w[G2 + tid] = g2[tid]; s_w[BB2 + tid] = bb2[tid]; }
    if (tid < 15) s_w[W3 + tid] = w3[tid];
    if (tid == 0) { s_w[B3] = b3[0]; s_w[G3] = g3[0]; s_w[BB3] = bb3[0]; }

    const int x = xidx[0];
#pragma unroll
    for (int c = 0; c < 4; ++c) s_pre[c][l] = hstate[c * 512 + l];
    s_pre[4][l] = emb[(size_t)x * 512 + l];
    __syncthreads();

    // ---- conv1 (5->32) ----
    float px[5][3];
#pragma unroll
    for (int ic = 0; ic < 5; ++ic) {
        px[ic][0] = (l > 0)   ? s_pre[ic][l-1] : 0.f;
        px[ic][1] =             s_pre[ic][l];
        px[ic][2] = (l < 511) ? s_pre[ic][l+1] : 0.f;
    }
#pragma unroll 4
    for (int oc = 0; oc < 32; ++oc) {
        float a = s_w[B1 + oc];
#pragma unroll
        for (int ic = 0; ic < 5; ++ic)
#pragma unroll
            for (int k = 0; k < 3; ++k)
                a += s_w[W1 + oc*15 + ic*3 + k] * px[ic][k];
        s_y[oc][l] = a;
    }
    __syncthreads();
#pragma unroll
    for (int t = 0; t < 4; ++t) {
        const int oc = wid * 4 + t;
        float s = 0.f, s2 = 0.f;
#pragma unroll
        for (int j = 0; j < 8; ++j) { float v = s_y[oc][lane + j*64]; s += v; s2 += v*v; }
        s = wave_rsum(s); s2 = wave_rsum(s2);
        if (lane == 0) { float m = s/512.f, var = s2/512.f - m*m; s_stat[oc][0] = m; s_stat[oc][1] = rsqrtf(var + 1e-5f); }
    }
    __syncthreads();
#pragma unroll 4
    for (int oc = 0; oc < 32; ++oc)
        s_y[oc][l] = fmaxf((s_y[oc][l] - s_stat[oc][0]) * s_stat[oc][1] * s_w[G1+oc] + s_w[BB1+oc], 0.f);
    __syncthreads();

    // ---- conv2 (32->5) + residual ----
    float y2[5];
#pragma unroll
    for (int oc = 0; oc < 5; ++oc) y2[oc] = s_w[B2 + oc];
#pragma unroll 2
    for (int ic = 0; ic < 32; ++ic) {
        float c0 = (l > 0)   ? s_y[ic][l-1] : 0.f;
        float c1 =             s_y[ic][l];
        float c2 = (l < 511) ? s_y[ic][l+1] : 0.f;
#pragma unroll
        for (int oc = 0; oc < 5; ++oc) {
            const int base = W2 + (oc*32 + ic)*3;
            y2[oc] += s_w[base]*c0 + s_w[base+1]*c1 + s_w[base+2]*c2;
        }
    }
#pragma unroll
    for (int oc = 0; oc < 5; ++oc) y2[oc] += s_pre[oc][l];
    __syncthreads();
#pragma unroll
    for (int oc = 0; oc < 5; ++oc) s_y[oc][l] = y2[oc];
    __syncthreads();
    if (wid < 5) {
        const int oc = wid;
        float s = 0.f, s2 = 0.f;
#pragma unroll
        for (int j = 0; j < 8; ++j) { float v = s_y[oc][lane + j*64]; s += v; s2 += v*v; }
        s = wave_rsum(s); s2 = wave_rsum(s2);
        if (lane == 0) { float m = s/512.f, var = s2/512.f - m*m; s_stat[oc][0] = m; s_stat[oc][1] = rsqrtf(var + 1e-5f); }
    }
    __syncthreads();
#pragma unroll
    for (int oc = 0; oc < 5; ++oc)
        s_pre[oc][l] = fmaxf((y2[oc] - s_stat[oc][0]) * s_stat[oc][1] * s_w[G2+oc] + s_w[BB2+oc], 0.f);
    __syncthreads();

    // ---- conv3 (5->1) ----
    float a3 = s_w[B3];
#pragma unroll
    for (int ic = 0; ic < 5; ++ic) {
        float c0 = (l > 0)   ? s_pre[ic][l-1] : 0.f;
        float c1 =             s_pre[ic][l];
        float c2 = (l < 511) ? s_pre[ic][l+1] : 0.f;
        a3 += s_w[W3+ic*3]*c0 + s_w[W3+ic*3+1]*c1 + s_w[W3+ic*3+2]*c2;
    }
    s_y[0][l] = a3;
    __syncthreads();
    if (wid == 0) {
        float s = 0.f, s2 = 0.f;
#pragma unroll
        for (int j = 0; j < 8; ++j) { float v = s_y[0][lane + j*64]; s += v; s2 += v*v; }
        s = wave_rsum(s); s2 = wave_rsum(s2);
        if (lane == 0) { float m = s/512.f, var = s2/512.f - m*m; s_stat[0][0] = m; s_stat[0][1] = rsqrtf(var + 1e-5f); }
    }
    __syncthreads();
    ws[WSF_Q + l] = fmaxf((a3 - s_stat[0][0]) * s_stat[0][1] * s_w[G3] + s_w[BB3], 0.f);
}

// =====================================================================
// K2: fused attention.  64 blocks x 256.  (R6-proven)
// =====================================================================
__global__ __launch_bounds__(256) void k_att(
    const float* __restrict__ attw, const float* __restrict__ attb,
    const float* __restrict__ enc, float* __restrict__ ws)
{
    __shared__ float s_e[32];
    __shared__ float s_d[4];
    const int tid = threadIdx.x, lane = tid & 63, wid = tid >> 6;
    const int jc = blockIdx.x;

    float q0[4], q1[4];
#pragma unroll
    for (int j = 0; j < 4; ++j) {
        q0[j] = ws[WSF_Q + lane*4 + j];
        q1[j] = ws[WSF_Q + 256 + lane*4 + j];
    }
    float dpart = 0.f;
#pragma unroll 4
    for (int r = 0; r < 8; ++r) {
        const int row = jc * 32 + wid * 8 + r;
        f32x4 w0 = *(const f32x4*)(attw + (size_t)row*512 + lane*4);
        f32x4 w1 = *(const f32x4*)(attw + (size_t)row*512 + 256 + lane*4);
        float a = 0.f;
#pragma unroll
        for (int j = 0; j < 4; ++j) a += w0[j]*q0[j] + w1[j]*q1[j];
        a = wave_rsum(a);
        if (lane == 0) {
            float e = __expf(a + attb[row]);   // |logit| << 80: exp-safe (R5/R6)
            s_e[wid*8 + r] = e;
            dpart += e;
        }
    }
    if (lane == 0) s_d[wid] = dpart;
    __syncthreads();
    if (tid == 0) ws[WSF_ADEN + jc] = s_d[0] + s_d[1] + s_d[2] + s_d[3];

    const int col = tid * 4;
    const float* ep = enc + (size_t)(jc * 32) * 1024 + col;
    f32x4 acc = {0.f, 0.f, 0.f, 0.f};
#pragma unroll 8
    for (int jj = 0; jj < 32; ++jj) {
        f32x4 v = *(const f32x4*)(ep + (size_t)jj * 1024);
        acc += s_e[jj] * v;
    }
    *(f32x4*)(ws + WSF_APART + jc * 1024 + col) = acc;
}

// =====================================================================
// K3: post-attention conv stack.  1 block x 512 threads.
// Zeroes the gru4 barrier slots (stream order guarantees visibility).
// =====================================================================
__global__ __launch_bounds__(512) void k_post(
    const float* __restrict__ emb, const int* __restrict__ xidx,
    const float* __restrict__ w4, const float* __restrict__ b4,
    const float* __restrict__ w5, const float* __restrict__ b5,
    const float* __restrict__ w6, const float* __restrict__ b6,
    const float* __restrict__ g4, const float* __restrict__ bb4,
    const float* __restrict__ g5, const float* __restrict__ bb5,
    const float* __restrict__ g6, const float* __restrict__ bb6,
    float* __restrict__ ws)
{
    constexpr int W4 = 0, B4 = 288, G4 = 320, BB4 = 352;
    constexpr int W5 = 384, B5 = 672, G5 = 675, BB5 = 678;
    constexpr int W6 = 681, B6 = 690, G6 = 691, BB6 = 692, NW = 693;
    __shared__ float s_w[NW];
    __shared__ float s_com[3][512];
    __shared__ float s_y[32][512];
    __shared__ float s_stat[32][2];
    const int tid = threadIdx.x, lane = tid & 63, wid = tid >> 6, l = tid;

    if (tid < 64) reinterpret_cast<int*>(ws + WSF_BAR)[tid] = 0;   // barrier init

    if (tid < 288) s_w[W4 + tid] = w4[tid];
    if (tid < 32) { s_w[B4 + tid] = b4[tid]; s_w[G4 + tid] = g4[tid]; s_w[BB4 + tid] = bb4[tid]; }
    if (tid < 288) s_w[W5 + tid] = w5[tid];
    if (tid < 3) { s_w[B5 + tid] = b5[tid]; s_w[G5 + tid] = g5[tid]; s_w[BB5 + tid] = bb5[tid]; }
    if (tid < 9) s_w[W6 + tid] = w6[tid];
    if (tid == 0) { s_w[B6] = b6[0]; s_w[G6] = g6[0]; s_w[BB6] = bb6[0]; }

    float den = 0.f;
#pragma unroll 8
    for (int i = 0; i < 64; ++i) den += ws[WSF_ADEN + i];
    const float invS = 1.0f / den;
    float a0 = 0.f, a1 = 0.f;
#pragma unroll 8
    for (int p = 0; p < 64; ++p) {
        a0 += ws[WSF_APART + p*1024 + l];
        a1 += ws[WSF_APART + p*1024 + 512 + l];
    }
    const int x = xidx[0];
    s_com[0][l] = a0 * invS;
    s_com[1][l] = a1 * invS;
    s_com[2][l] = emb[(size_t)x*512 + l];
    __syncthreads();

    // ---- conv4 (3->32) ----
    float px[3][3];
#pragma unroll
    for (int ic = 0; ic < 3; ++ic) {
        px[ic][0] = (l > 0)   ? s_com[ic][l-1] : 0.f;
        px[ic][1] =             s_com[ic][l];
        px[ic][2] = (l < 511) ? s_com[ic][l+1] : 0.f;
    }
#pragma unroll 4
    for (int oc = 0; oc < 32; ++oc) {
        float a = s_w[B4 + oc];
#pragma unroll
        for (int ic = 0; ic < 3; ++ic)
#pragma unroll
            for (int k = 0; k < 3; ++k)
                a += s_w[W4 + oc*9 + ic*3 + k] * px[ic][k];
        s_y[oc][l] = a;
    }
    __syncthreads();
#pragma unroll
    for (int t = 0; t < 4; ++t) {
        const int oc = wid * 4 + t;
        float s = 0.f, s2 = 0.f;
#pragma unroll
        for (int j = 0; j < 8; ++j) { float v = s_y[oc][lane + j*64]; s += v; s2 += v*v; }
        s = wave_rsum(s); s2 = wave_rsum(s2);
        if (lane == 0) { float m = s/512.f, var = s2/512.f - m*m; s_stat[oc][0] = m; s_stat[oc][1] = rsqrtf(var + 1e-5f); }
    }
    __syncthreads();
#pragma unroll 4
    for (int oc = 0; oc < 32; ++oc)
        s_y[oc][l] = fmaxf((s_y[oc][l] - s_stat[oc][0]) * s_stat[oc][1] * s_w[G4+oc] + s_w[BB4+oc], 0.f);
    __syncthreads();

    // ---- conv5 (32->3) + residual ----
    float y2[3];
#pragma unroll
    for (int oc = 0; oc < 3; ++oc) y2[oc] = s_w[B5 + oc];
#pragma unroll 2
    for (int ic = 0; ic < 32; ++ic) {
        float c0 = (l > 0)   ? s_y[ic][l-1] : 0.f;
        float c1 =             s_y[ic][l];
        float c2 = (l < 511) ? s_y[ic][l+1] : 0.f;
#pragma unroll
        for (int oc = 0; oc < 3; ++oc) {
            const int base = W5 + (oc*32 + ic)*3;
            y2[oc] += s_w[base]*c0 + s_w[base+1]*c1 + s_w[base+2]*c2;
        }
    }
#pragma unroll
    for (int oc = 0; oc < 3; ++oc) y2[oc] += s_com[oc][l];
    __syncthreads();
#pragma unroll
    for (int oc = 0; oc < 3; ++oc) s_y[oc][l] = y2[oc];
    __syncthreads();
    if (wid < 3) {
        const int oc = wid;
        float s = 0.f, s2 = 0.f;
#pragma unroll
        for (int j = 0; j < 8; ++j) { float v = s_y[oc][lane + j*64]; s += v; s2 += v*v; }
        s = wave_rsum(s); s2 = wave_rsum(s2);
        if (lane == 0) { float m = s/512.f, var = s2/512.f - m*m; s_stat[oc][0] = m; s_stat[oc][1] = rsqrtf(var + 1e-5f); }
    }
    __syncthreads();
#pragma unroll
    for (int oc = 0; oc < 3; ++oc)
        s_com[oc][l] = fmaxf((y2[oc] - s_stat[oc][0]) * s_stat[oc][1] * s_w[G5+oc] + s_w[BB5+oc], 0.f);
    __syncthreads();

    // ---- conv6 (3->1) ----
    float a6 = s_w[B6];
#pragma unroll
    for (int ic = 0; ic < 3; ++ic) {
        float c0 = (l > 0)   ? s_com[ic][l-1] : 0.f;
        float c1 =             s_com[ic][l];
        float c2 = (l < 511) ? s_com[ic][l+1] : 0.f;
        a6 += s_w[W6+ic*3]*c0 + s_w[W6+ic*3+1]*c1 + s_w[W6+ic*3+2]*c2;
    }
    s_y[0][l] = a6;
    __syncthreads();
    if (wid == 0) {
        float s = 0.f, s2 = 0.f;
#pragma unroll
        for (int j = 0; j < 8; ++j) { float v = s_y[0][lane + j*64]; s += v; s2 += v*v; }
        s = wave_rsum(s); s2 = wave_rsum(s2);
        if (lane == 0) { float m = s/512.f, var = s2/512.f - m*m; s_stat[0][0] = m; s_stat[0][1] = rsqrtf(var + 1e-5f); }
    }
    __syncthreads();
    ws[WSF_XT + l] = fmaxf((a6 - s_stat[0][0]) * s_stat[0][1] * s_w[G6] + s_w[BB6], 0.f);
}

// =====================================================================
// K4: all 4 GRU layers, one PLAIN launch.  64 blocks x 256, gbar between
// layers.  (R8-proven cheap: plain launch + 64-block gbar.)
// =====================================================================
__global__ __launch_bounds__(256) void k_gru4(
    const float* __restrict__ wih_, const float* __restrict__ whh_,
    const float* __restrict__ bih_, const float* __restrict__ bhh_,
    const float* __restrict__ hstate,
    float* ws, float* __restrict__ out)
{
    const int tid = threadIdx.x, lane = tid & 63, wid = tid >> 6;
    const int i0 = blockIdx.x * 8;
    __shared__ float s_g[8][6];

#pragma unroll 1
    for (int l = 0; l < 4; ++l) {
        const float* wih = wih_ + (size_t)l * 1536 * 512;
        const float* whh = whh_ + (size_t)l * 1536 * 512;
        const float* bih = bih_ + l * 1536;
        const float* bhh = bhh_ + l * 1536;
        const float* hp  = hstate + l * 512;
        const float* xt_in = ws + WSF_XT + l * 512;
        float* xt_out = ws + WSF_XT + (l + 1) * 512;

        float xq0[4], xq1[4], hq0[4], hq1[4];
#pragma unroll
        for (int j = 0; j < 4; ++j) {
            xq0[j] = xt_in[lane*4 + j];
            xq1[j] = xt_in[256 + lane*4 + j];
            hq0[j] = hp[lane*4 + j];
            hq1[j] = hp[256 + lane*4 + j];
        }
#pragma unroll
        for (int t = 0; t < 2; ++t) {
            const int ii = wid * 2 + t;
            const int i = i0 + ii;
            float a[6] = {0.f, 0.f, 0.f, 0.f, 0.f, 0.f};
#pragma unroll
            for (int g = 0; g < 3; ++g) {
                const float* wr = wih + (size_t)(i + g*512) * 512;
                f32x4 w0 = *(const f32x4*)(wr + lane*4);
                f32x4 w1 = *(const f32x4*)(wr + 256 + lane*4);
#pragma unroll
                for (int j = 0; j < 4; ++j) a[g] += w0[j]*xq0[j] + w1[j]*xq1[j];
            }
#pragma unroll
            for (int g = 0; g < 3; ++g) {
                const float* wr = whh + (size_t)(i + g*512) * 512;
                f32x4 w0 = *(const f32x4*)(wr + lane*4);
                f32x4 w1 = *(const f32x4*)(wr + 256 + lane*4);
#pragma unroll
                for (int j = 0; j < 4; ++j) a[3+g] += w0[j]*hq0[j] + w1[j]*hq1[j];
            }
#pragma unroll
            for (int g = 0; g < 6; ++g) a[g] = wave_rsum(a[g]);
            if (lane == 0) {
#pragma unroll
                for (int g = 0; g < 6; ++g) s_g[ii][g] = a[g];
            }
        }
        __syncthreads();
        if (tid < 8) {
            const int i = i0 + tid;
            float ir = s_g[tid][0] + bih[i];
            float iz = s_g[tid][1] + bih[i + 512];
            float in_ = s_g[tid][2] + bih[i + 1024];
            float hr = s_g[tid][3] + bhh[i];
            float hz = s_g[tid][4] + bhh[i + 512];
            float hn = s_g[tid][5] + bhh[i + 1024];
            float r = sigm(ir + hr);
            float z = sigm(iz + hz);
            float n = tanhf(in_ + r * hn);
            float h = (1.f - z) * n + z * hp[i];
            xt_out[i] = h;
            out[NVOCAB + l*512 + i] = h;
        }
        if (l < 3) gbar(ws, l, 64);
        else __syncthreads();
    }
}

// =====================================================================
// K5: vocab GEMV + per-block online (max, sum-exp).  786 x 256.
// (R6-proven; NO cross-block spin — R8 showed that is a coherence storm.)
// =====================================================================
__global__ __launch_bounds__(256) void k_vocab(
    const float* __restrict__ low, const float* __restrict__ lob,
    float* __restrict__ ws)
{
    const int tid = threadIdx.x, lane = tid & 63, wid = tid >> 6;
    float q0[4], q1[4];
#pragma unroll
    for (int j = 0; j < 4; ++j) {
        q0[j] = ws[WSF_XT + 4*512 + lane*4 + j];
        q1[j] = ws[WSF_XT + 4*512 + 256 + lane*4 + j];
    }
    const int row0 = blockIdx.x * 64 + wid * 16;
    float m = -INFINITY, s = 0.0f;
#pragma unroll 4
    for (int r = 0; r < 16; ++r) {
        const int row = row0 + r;
        if (row < NVOCAB) {
            f32x4 w0 = *(const f32x4*)(low + (size_t)row*512 + lane*4);
            f32x4 w1 = *(const f32x4*)(low + (size_t)row*512 + 256 + lane*4);
            float a = 0.f;
#pragma unroll
            for (int j = 0; j < 4; ++j) a += w0[j]*q0[j] + w1[j]*q1[j];
            a = wave_rsum(a);
            if (lane == 0) {
                float v = a + lob[row];
                ws[WSF_LOGV + row] = v;
                if (v > m) { s = s * __expf(m - v) + 1.0f; m = v; }
                else       { s += __expf(v - m); }
            }
        }
    }
    __shared__ float smx[4], ssx[4];
    if (lane == 0) { smx[wid] = m; ssx[wid] = s; }
    __syncthreads();
    if (tid == 0) {
        float M = -INFINITY, S = 0.0f;
#pragma unroll
        for (int w = 0; w < 4; ++w) {
            float mb = smx[w], sb = ssx[w];
            if (sb > 0.0f) {
                if (mb > M) { S = S * __expf(M - mb) + sb; M = mb; }
                else        { S += sb * __expf(mb - M); }
            }
        }
        ws[WSF_PM + blockIdx.x] = M;
        ws[WSF_PS + blockIdx.x] = S;
    }
}

// =====================================================================
// K6: redundant deterministic LSE + write log-probs.  197 blocks x 256
// =====================================================================
__global__ __launch_bounds__(256) void k_outlse(
    const float* __restrict__ ws, float* __restrict__ out)
{
    __shared__ float smx[256], ssx[256];
    const int tid = threadIdx.x;
    float M = -INFINITY, S = 0.0f;
    for (int i = tid; i < NBLK_V; i += 256) {
        float mb = ws[WSF_PM + i], sb = ws[WSF_PS + i];
        if (mb > M) { S = S * __expf(M - mb) + sb; M = mb; }
        else        { S += sb * __expf(mb - M); }
    }
    smx[tid] = M; ssx[tid] = S;
    __syncthreads();
    for (int st = 128; st > 0; st >>= 1) {
        if (tid < st) {
            float mb = smx[tid + st], sb = ssx[tid + st];
            if (sb > 0.0f) {
                if (mb > smx[tid]) { ssx[tid] = ssx[tid] * __expf(smx[tid] - mb) + sb; smx[tid] = mb; }
                else               { ssx[tid] += sb * __expf(mb - smx[tid]); }
            }
        }
        __syncthreads();
    }
    const float lse = smx[0] + logf(ssx[0]);
    const int i = blockIdx.x * 256 + tid;
    if (i < NVOCAB) out[i] = ws[WSF_LOGV + i] - lse;
}

// =====================================================================
extern "C" void kernel_launch(void* const* d_in, const int* in_sizes, int n_in,
                              void* d_out, int out_size, void* d_ws, size_t ws_size,
                              hipStream_t stream)
{
    (void)in_sizes; (void)n_in; (void)out_size; (void)ws_size;
    const float* emb     = (const float*)d_in[0];
    const float* conv1_w = (const float*)d_in[1];  const float* conv1_b = (const float*)d_in[2];
    const float* conv2_w = (const float*)d_in[3];  const float* conv2_b = (const float*)d_in[4];
    const float* conv3_w = (const float*)d_in[5];  const float* conv3_b = (const float*)d_in[6];
    const float* conv4_w = (const float*)d_in[7];  const float* conv4_b = (const float*)d_in[8];
    const float* conv5_w = (const float*)d_in[9];  const float* conv5_b = (const float*)d_in[10];
    const float* conv6_w = (const float*)d_in[11]; const float* conv6_b = (const float*)d_in[12];
    const float* bn1_g = (const float*)d_in[13];   const float* bn1_b = (const float*)d_in[14];
    const float* bn2_g = (const float*)d_in[15];   const float* bn2_b = (const float*)d_in[16];
    const float* bn3_g = (const float*)d_in[17];   const float* bn3_b = (const float*)d_in[18];
    const float* bn4_g = (const float*)d_in[19];   const float* bn4_b = (const float*)d_in[20];
    const float* bn5_g = (const float*)d_in[21];   const float* bn5_b = (const float*)d_in[22];
    const float* bn6_g = (const float*)d_in[23];   const float* bn6_b = (const float*)d_in[24];
    const float* att_w = (const float*)d_in[25];   const float* att_b = (const float*)d_in[26];
    const float* gru_wih = (const float*)d_in[27]; const float* gru_whh = (const float*)d_in[28];
    const float* gru_bih = (const float*)d_in[29]; const float* gru_bhh = (const float*)d_in[30];
    const float* lo_w = (const float*)d_in[31];    const float* lo_b = (const float*)d_in[32];
    const float* h_state = (const float*)d_in[33];
    const float* enc = (const float*)d_in[34];
    const int* x = (const int*)d_in[35];

    float* ws = (float*)d_ws;
    float* out = (float*)d_out;

    k_pre<<<1, 512, 0, stream>>>(emb, x, h_state,
        conv1_w, conv1_b, conv2_w, conv2_b, conv3_w, conv3_b,
        bn1_g, bn1_b, bn2_g, bn2_b, bn3_g, bn3_b, ws);
    k_att<<<64, 256, 0, stream>>>(att_w, att_b, enc, ws);
    k_post<<<1, 512, 0, stream>>>(emb, x,
        conv4_w, conv4_b, conv5_w, conv5_b, conv6_w, conv6_b,
        bn4_g, bn4_b, bn5_g, bn5_b, bn6_g, bn6_b, ws);
    k_gru4<<<64, 256, 0, stream>>>(gru_wih, gru_whh, gru_bih, gru_bhh, h_state, ws, out);
    k_vocab<<<NBLK_V, 256, 0, stream>>>(lo_w, lo_b, ws);
    k_outlse<<<197, 256, 0, stream>>>(ws, out);
}

// Round 10
// 101.135 us; speedup vs baseline: 2.9525x; 1.2014x over previous
//
#include <hip/hip_runtime.h>
#include <hip/hip_bf16.h>

typedef __attribute__((ext_vector_type(4))) float f32x4;

// ---------------- workspace layout (fp32 elements) ----------------
constexpr int WSF_Q     = 0;        // 512    attention query (conv3 out)
constexpr int WSF_ADEN  = 512;      // 64     per-chunk exp-sum
constexpr int WSF_APART = 1024;     // 64*1024 per-chunk PV partials (unnormalized)
constexpr int WSF_XT    = 66560;    // 5*512  xt chain
constexpr int WSF_LOGV  = 69120;    // 50257  vocab logits
constexpr int WSF_PM    = 119424;   // 786    per-block max
constexpr int WSF_PS    = 120320;   // 786    per-block sum-exp
constexpr int WSF_GH    = 121344;   // 4*1536 Whh*h + bhh (computed in k_att's shadow)
constexpr int NVOCAB    = 50257;
constexpr int NBLK_V    = 786;      // ceil(50257/64)

__device__ __forceinline__ float wave_rsum(float v) {
#pragma unroll
    for (int o = 32; o > 0; o >>= 1) v += __shfl_down(v, o);
    return v; // lane 0 holds sum
}
__device__ __forceinline__ float sigm(float x) { return 1.0f / (1.0f + __expf(-x)); }

// =====================================================================
// K1: pre-attention conv stack.  1 block x 512 threads (thread = position)
// =====================================================================
__global__ __launch_bounds__(512) void k_pre(
    const float* __restrict__ emb, const int* __restrict__ xidx,
    const float* __restrict__ hstate,
    const float* __restrict__ w1, const float* __restrict__ b1,
    const float* __restrict__ w2, const float* __restrict__ b2,
    const float* __restrict__ w3, const float* __restrict__ b3,
    const float* __restrict__ g1, const float* __restrict__ bb1,
    const float* __restrict__ g2, const float* __restrict__ bb2,
    const float* __restrict__ g3, const float* __restrict__ bb3,
    float* __restrict__ ws)
{
    constexpr int W1 = 0, B1 = 480, G1 = 512, BB1 = 544;
    constexpr int W2 = 576, B2 = 1056, G2 = 1061, BB2 = 1066;
    constexpr int W3 = 1071, B3 = 1086, G3 = 1087, BB3 = 1088, NW = 1089;
    __shared__ float s_w[NW];
    __shared__ float s_pre[5][512];
    __shared__ float s_y[32][512];
    __shared__ float s_stat[32][2];
    const int tid = threadIdx.x, lane = tid & 63, wid = tid >> 6, l = tid;

    if (tid < 480) s_w[W1 + tid] = w1[tid];
    if (tid < 32) { s_w[B1 + tid] = b1[tid]; s_w[G1 + tid] = g1[tid]; s_w[BB1 + tid] = bb1[tid]; }
    if (tid < 480) s_w[W2 + tid] = w2[tid];
    if (tid < 5) { s_w[B2 + tid] = b2[tid]; s_w[G2 + tid] = g2[tid]; s_w[BB2 + tid] = bb2[tid]; }
    if (tid < 15) s_w[W3 + tid] = w3[tid];
    if (tid == 0) { s_w[B3] = b3[0]; s_w[G3] = g3[0]; s_w[BB3] = bb3[0]; }

    const int x = xidx[0];
#pragma unroll
    for (int c = 0; c < 4; ++c) s_pre[c][l] = hstate[c * 512 + l];
    s_pre[4][l] = emb[(size_t)x * 512 + l];
    __syncthreads();

    // ---- conv1 (5->32) ----
    float px[5][3];
#pragma unroll
    for (int ic = 0; ic < 5; ++ic) {
        px[ic][0] = (l > 0)   ? s_pre[ic][l-1] : 0.f;
        px[ic][1] =             s_pre[ic][l];
        px[ic][2] = (l < 511) ? s_pre[ic][l+1] : 0.f;
    }
#pragma unroll 4
    for (int oc = 0; oc < 32; ++oc) {
        float a = s_w[B1 + oc];
#pragma unroll
        for (int ic = 0; ic < 5; ++ic)
#pragma unroll
            for (int k = 0; k < 3; ++k)
                a += s_w[W1 + oc*15 + ic*3 + k] * px[ic][k];
        s_y[oc][l] = a;
    }
    __syncthreads();
#pragma unroll
    for (int t = 0; t < 4; ++t) {
        const int oc = wid * 4 + t;
        float s = 0.f, s2 = 0.f;
#pragma unroll
        for (int j = 0; j < 8; ++j) { float v = s_y[oc][lane + j*64]; s += v; s2 += v*v; }
        s = wave_rsum(s); s2 = wave_rsum(s2);
        if (lane == 0) { float m = s/512.f, var = s2/512.f - m*m; s_stat[oc][0] = m; s_stat[oc][1] = rsqrtf(var + 1e-5f); }
    }
    __syncthreads();
#pragma unroll 4
    for (int oc = 0; oc < 32; ++oc)
        s_y[oc][l] = fmaxf((s_y[oc][l] - s_stat[oc][0]) * s_stat[oc][1] * s_w[G1+oc] + s_w[BB1+oc], 0.f);
    __syncthreads();

    // ---- conv2 (32->5) + residual ----
    float y2[5];
#pragma unroll
    for (int oc = 0; oc < 5; ++oc) y2[oc] = s_w[B2 + oc];
#pragma unroll 2
    for (int ic = 0; ic < 32; ++ic) {
        float c0 = (l > 0)   ? s_y[ic][l-1] : 0.f;
        float c1 =             s_y[ic][l];
        float c2 = (l < 511) ? s_y[ic][l+1] : 0.f;
#pragma unroll
        for (int oc = 0; oc < 5; ++oc) {
            const int base = W2 + (oc*32 + ic)*3;
            y2[oc] += s_w[base]*c0 + s_w[base+1]*c1 + s_w[base+2]*c2;
        }
    }
#pragma unroll
    for (int oc = 0; oc < 5; ++oc) y2[oc] += s_pre[oc][l];
    __syncthreads();
#pragma unroll
    for (int oc = 0; oc < 5; ++oc) s_y[oc][l] = y2[oc];
    __syncthreads();
    if (wid < 5) {
        const int oc = wid;
        float s = 0.f, s2 = 0.f;
#pragma unroll
        for (int j = 0; j < 8; ++j) { float v = s_y[oc][lane + j*64]; s += v; s2 += v*v; }
        s = wave_rsum(s); s2 = wave_rsum(s2);
        if (lane == 0) { float m = s/512.f, var = s2/512.f - m*m; s_stat[oc][0] = m; s_stat[oc][1] = rsqrtf(var + 1e-5f); }
    }
    __syncthreads();
#pragma unroll
    for (int oc = 0; oc < 5; ++oc)
        s_pre[oc][l] = fmaxf((y2[oc] - s_stat[oc][0]) * s_stat[oc][1] * s_w[G2+oc] + s_w[BB2+oc], 0.f);
    __syncthreads();

    // ---- conv3 (5->1) ----
    float a3 = s_w[B3];
#pragma unroll
    for (int ic = 0; ic < 5; ++ic) {
        float c0 = (l > 0)   ? s_pre[ic][l-1] : 0.f;
        float c1 =             s_pre[ic][l];
        float c2 = (l < 511) ? s_pre[ic][l+1] : 0.f;
        a3 += s_w[W3+ic*3]*c0 + s_w[W3+ic*3+1]*c1 + s_w[W3+ic*3+2]*c2;
    }
    s_y[0][l] = a3;
    __syncthreads();
    if (wid == 0) {
        float s = 0.f, s2 = 0.f;
#pragma unroll
        for (int j = 0; j < 8; ++j) { float v = s_y[0][lane + j*64]; s += v; s2 += v*v; }
        s = wave_rsum(s); s2 = wave_rsum(s2);
        if (lane == 0) { float m = s/512.f, var = s2/512.f - m*m; s_stat[0][0] = m; s_stat[0][1] = rsqrtf(var + 1e-5f); }
    }
    __syncthreads();
    ws[WSF_Q + l] = fmaxf((a3 - s_stat[0][0]) * s_stat[0][1] * s_w[G3] + s_w[BB3], 0.f);
}

// =====================================================================
// K2: fused attention + (in shadow) GRU hidden-side gates.
// 256 blocks x 256: blocks 0..63 attention chunk jc=bid (R6-proven);
// blocks 64..255: gh = Whh*h + bhh (input-only dependent; 32 rows/block).
// =====================================================================
__global__ __launch_bounds__(256) void k_att(
    const float* __restrict__ attw, const float* __restrict__ attb,
    const float* __restrict__ enc,
    const float* __restrict__ whh, const float* __restrict__ bhh,
    const float* __restrict__ hstate,
    float* __restrict__ ws)
{
    __shared__ float s_e[32];
    __shared__ float s_d[4];
    const int tid = threadIdx.x, lane = tid & 63, wid = tid >> 6;
    const int bid = blockIdx.x;

    if (bid >= 64) {
        // ---- gruh: rows base..base+7 for this wave (block's 32 rows in one layer) ----
        const int base = (bid - 64) * 32 + wid * 8;
        const int l = base / 1536;
        const float* hp = hstate + l * 512;
        f32x4 h0 = *(const f32x4*)(hp + lane*4);
        f32x4 h1 = *(const f32x4*)(hp + 256 + lane*4);
#pragma unroll
        for (int r = 0; r < 8; ++r) {
            const int R = base + r;
            const float* wr = whh + (size_t)R * 512;
            f32x4 w0 = *(const f32x4*)(wr + lane*4);
            f32x4 w1 = *(const f32x4*)(wr + 256 + lane*4);
            float a = 0.f;
#pragma unroll
            for (int j = 0; j < 4; ++j) a += w0[j]*h0[j] + w1[j]*h1[j];
            a = wave_rsum(a);
            if (lane == 0) ws[WSF_GH + R] = a + bhh[R];
        }
        return;
    }

    // ---- attention chunk (R6-proven) ----
    const int jc = bid;
    float q0[4], q1[4];
#pragma unroll
    for (int j = 0; j < 4; ++j) {
        q0[j] = ws[WSF_Q + lane*4 + j];
        q1[j] = ws[WSF_Q + 256 + lane*4 + j];
    }
    float dpart = 0.f;
#pragma unroll 4
    for (int r = 0; r < 8; ++r) {
        const int row = jc * 32 + wid * 8 + r;
        f32x4 w0 = *(const f32x4*)(attw + (size_t)row*512 + lane*4);
        f32x4 w1 = *(const f32x4*)(attw + (size_t)row*512 + 256 + lane*4);
        float a = 0.f;
#pragma unroll
        for (int j = 0; j < 4; ++j) a += w0[j]*q0[j] + w1[j]*q1[j];
        a = wave_rsum(a);
        if (lane == 0) {
            float e = __expf(a + attb[row]);   // |logit| << 80: exp-safe (R5/R6)
            s_e[wid*8 + r] = e;
            dpart += e;
        }
    }
    if (lane == 0) s_d[wid] = dpart;
    __syncthreads();
    if (tid == 0) ws[WSF_ADEN + jc] = s_d[0] + s_d[1] + s_d[2] + s_d[3];

    const int col = tid * 4;
    const float* ep = enc + (size_t)(jc * 32) * 1024 + col;
    f32x4 acc = {0.f, 0.f, 0.f, 0.f};
#pragma unroll 8
    for (int jj = 0; jj < 32; ++jj) {
        f32x4 v = *(const f32x4*)(ep + (size_t)jj * 1024);
        acc += s_e[jj] * v;
    }
    *(f32x4*)(ws + WSF_APART + jc * 1024 + col) = acc;
}

// =====================================================================
// K3: post-attention conv stack.  1 block x 512 threads.
// =====================================================================
__global__ __launch_bounds__(512) void k_post(
    const float* __restrict__ emb, const int* __restrict__ xidx,
    const float* __restrict__ w4, const float* __restrict__ b4,
    const float* __restrict__ w5, const float* __restrict__ b5,
    const float* __restrict__ w6, const float* __restrict__ b6,
    const float* __restrict__ g4, const float* __restrict__ bb4,
    const float* __restrict__ g5, const float* __restrict__ bb5,
    const float* __restrict__ g6, const float* __restrict__ bb6,
    float* __restrict__ ws)
{
    constexpr int W4 = 0, B4 = 288, G4 = 320, BB4 = 352;
    constexpr int W5 = 384, B5 = 672, G5 = 675, BB5 = 678;
    constexpr int W6 = 681, B6 = 690, G6 = 691, BB6 = 692, NW = 693;
    __shared__ float s_w[NW];
    __shared__ float s_com[3][512];
    __shared__ float s_y[32][512];
    __shared__ float s_stat[32][2];
    const int tid = threadIdx.x, lane = tid & 63, wid = tid >> 6, l = tid;

    if (tid < 288) s_w[W4 + tid] = w4[tid];
    if (tid < 32) { s_w[B4 + tid] = b4[tid]; s_w[G4 + tid] = g4[tid]; s_w[BB4 + tid] = bb4[tid]; }
    if (tid < 288) s_w[W5 + tid] = w5[tid];
    if (tid < 3) { s_w[B5 + tid] = b5[tid]; s_w[G5 + tid] = g5[tid]; s_w[BB5 + tid] = bb5[tid]; }
    if (tid < 9) s_w[W6 + tid] = w6[tid];
    if (tid == 0) { s_w[B6] = b6[0]; s_w[G6] = g6[0]; s_w[BB6] = bb6[0]; }

    float den = 0.f;
#pragma unroll 8
    for (int i = 0; i < 64; ++i) den += ws[WSF_ADEN + i];
    const float invS = 1.0f / den;
    float a0 = 0.f, a1 = 0.f;
#pragma unroll 8
    for (int p = 0; p < 64; ++p) {
        a0 += ws[WSF_APART + p*1024 + l];
        a1 += ws[WSF_APART + p*1024 + 512 + l];
    }
    const int x = xidx[0];
    s_com[0][l] = a0 * invS;
    s_com[1][l] = a1 * invS;
    s_com[2][l] = emb[(size_t)x*512 + l];
    __syncthreads();

    // ---- conv4 (3->32) ----
    float px[3][3];
#pragma unroll
    for (int ic = 0; ic < 3; ++ic) {
        px[ic][0] = (l > 0)   ? s_com[ic][l-1] : 0.f;
        px[ic][1] =             s_com[ic][l];
        px[ic][2] = (l < 511) ? s_com[ic][l+1] : 0.f;
    }
#pragma unroll 4
    for (int oc = 0; oc < 32; ++oc) {
        float a = s_w[B4 + oc];
#pragma unroll
        for (int ic = 0; ic < 3; ++ic)
#pragma unroll
            for (int k = 0; k < 3; ++k)
                a += s_w[W4 + oc*9 + ic*3 + k] * px[ic][k];
        s_y[oc][l] = a;
    }
    __syncthreads();
#pragma unroll
    for (int t = 0; t < 4; ++t) {
        const int oc = wid * 4 + t;
        float s = 0.f, s2 = 0.f;
#pragma unroll
        for (int j = 0; j < 8; ++j) { float v = s_y[oc][lane + j*64]; s += v; s2 += v*v; }
        s = wave_rsum(s); s2 = wave_rsum(s2);
        if (lane == 0) { float m = s/512.f, var = s2/512.f - m*m; s_stat[oc][0] = m; s_stat[oc][1] = rsqrtf(var + 1e-5f); }
    }
    __syncthreads();
#pragma unroll 4
    for (int oc = 0; oc < 32; ++oc)
        s_y[oc][l] = fmaxf((s_y[oc][l] - s_stat[oc][0]) * s_stat[oc][1] * s_w[G4+oc] + s_w[BB4+oc], 0.f);
    __syncthreads();

    // ---- conv5 (32->3) + residual ----
    float y2[3];
#pragma unroll
    for (int oc = 0; oc < 3; ++oc) y2[oc] = s_w[B5 + oc];
#pragma unroll 2
    for (int ic = 0; ic < 32; ++ic) {
        float c0 = (l > 0)   ? s_y[ic][l-1] : 0.f;
        float c1 =             s_y[ic][l];
        float c2 = (l < 511) ? s_y[ic][l+1] : 0.f;
#pragma unroll
        for (int oc = 0; oc < 3; ++oc) {
            const int base = W5 + (oc*32 + ic)*3;
            y2[oc] += s_w[base]*c0 + s_w[base+1]*c1 + s_w[base+2]*c2;
        }
    }
#pragma unroll
    for (int oc = 0; oc < 3; ++oc) y2[oc] += s_com[oc][l];
    __syncthreads();
#pragma unroll
    for (int oc = 0; oc < 3; ++oc) s_y[oc][l] = y2[oc];
    __syncthreads();
    if (wid < 3) {
        const int oc = wid;
        float s = 0.f, s2 = 0.f;
#pragma unroll
        for (int j = 0; j < 8; ++j) { float v = s_y[oc][lane + j*64]; s += v; s2 += v*v; }
        s = wave_rsum(s); s2 = wave_rsum(s2);
        if (lane == 0) { float m = s/512.f, var = s2/512.f - m*m; s_stat[oc][0] = m; s_stat[oc][1] = rsqrtf(var + 1e-5f); }
    }
    __syncthreads();
#pragma unroll
    for (int oc = 0; oc < 3; ++oc)
        s_com[oc][l] = fmaxf((y2[oc] - s_stat[oc][0]) * s_stat[oc][1] * s_w[G5+oc] + s_w[BB5+oc], 0.f);
    __syncthreads();

    // ---- conv6 (3->1) ----
    float a6 = s_w[B6];
#pragma unroll
    for (int ic = 0; ic < 3; ++ic) {
        float c0 = (l > 0)   ? s_com[ic][l-1] : 0.f;
        float c1 =             s_com[ic][l];
        float c2 = (l < 511) ? s_com[ic][l+1] : 0.f;
        a6 += s_w[W6+ic*3]*c0 + s_w[W6+ic*3+1]*c1 + s_w[W6+ic*3+2]*c2;
    }
    s_y[0][l] = a6;
    __syncthreads();
    if (wid == 0) {
        float s = 0.f, s2 = 0.f;
#pragma unroll
        for (int j = 0; j < 8; ++j) { float v = s_y[0][lane + j*64]; s += v; s2 += v*v; }
        s = wave_rsum(s); s2 = wave_rsum(s2);
        if (lane == 0) { float m = s/512.f, var = s2/512.f - m*m; s_stat[0][0] = m; s_stat[0][1] = rsqrtf(var + 1e-5f); }
    }
    __syncthreads();
    ws[WSF_XT + l] = fmaxf((a6 - s_stat[0][0]) * s_stat[0][1] * s_w[G6] + s_w[BB6], 0.f);
}

// =====================================================================
// K4: GRU input-side gates + cell update, one layer (R4-verified).
// 128 blocks x 256; wave = unit, 3 Wih row-dots; gh precomputed in k_att.
// =====================================================================
__global__ __launch_bounds__(256) void k_grux(
    const float* __restrict__ wih, const float* __restrict__ bih,
    const float* __restrict__ hstate,
    const float* __restrict__ xt_in, float* __restrict__ xt_out,
    float* __restrict__ hout, const float* __restrict__ gh, int layer)
{
    wih += (size_t)layer * 1536 * 512;
    bih += layer * 1536;
    const float* hp = hstate + layer * 512;

    const int tid = threadIdx.x, lane = tid & 63, wid = tid >> 6;
    float xq0[4], xq1[4];
#pragma unroll
    for (int j = 0; j < 4; ++j) {
        xq0[j] = xt_in[lane*4 + j];
        xq1[j] = xt_in[256 + lane*4 + j];
    }
    __shared__ float s_g[4][3];
    const int u = blockIdx.x * 4 + wid;   // unit 0..511
#pragma unroll
    for (int g = 0; g < 3; ++g) {
        const float* wr = wih + (size_t)(u + g*512) * 512;
        f32x4 w0 = *(const f32x4*)(wr + lane*4);
        f32x4 w1 = *(const f32x4*)(wr + 256 + lane*4);
        float a = 0.f;
#pragma unroll
        for (int j = 0; j < 4; ++j) a += w0[j]*xq0[j] + w1[j]*xq1[j];
        a = wave_rsum(a);
        if (lane == 0) s_g[wid][g] = a + bih[u + g*512];
    }
    __syncthreads();
    if (tid < 4) {
        const int i = blockIdx.x * 4 + tid;
        float r = sigm(s_g[tid][0] + gh[i]);
        float z = sigm(s_g[tid][1] + gh[i + 512]);
        float n = tanhf(s_g[tid][2] + r * gh[i + 1024]);
        float h = (1.f - z) * n + z * hp[i];
        xt_out[i] = h;
        hout[i] = h;
    }
}

// =====================================================================
// K5: vocab GEMV (nontemporal weight stream) + per-block (max, sum-exp).
// 786 blocks x 256.  (R6-proven; no cross-block sync.)
// =====================================================================
__global__ __launch_bounds__(256) void k_vocab(
    const float* __restrict__ low, const float* __restrict__ lob,
    float* __restrict__ ws)
{
    const int tid = threadIdx.x, lane = tid & 63, wid = tid >> 6;
    float q0[4], q1[4];
#pragma unroll
    for (int j = 0; j < 4; ++j) {
        q0[j] = ws[WSF_XT + 4*512 + lane*4 + j];
        q1[j] = ws[WSF_XT + 4*512 + 256 + lane*4 + j];
    }
    const int row0 = blockIdx.x * 64 + wid * 16;
    float m = -INFINITY, s = 0.0f;
#pragma unroll 4
    for (int r = 0; r < 16; ++r) {
        const int row = row0 + r;
        if (row < NVOCAB) {
            f32x4 w0 = __builtin_nontemporal_load((const f32x4*)(low + (size_t)row*512 + lane*4));
            f32x4 w1 = __builtin_nontemporal_load((const f32x4*)(low + (size_t)row*512 + 256 + lane*4));
            float a = 0.f;
#pragma unroll
            for (int j = 0; j < 4; ++j) a += w0[j]*q0[j] + w1[j]*q1[j];
            a = wave_rsum(a);
            if (lane == 0) {
                float v = a + lob[row];
                ws[WSF_LOGV + row] = v;
                if (v > m) { s = s * __expf(m - v) + 1.0f; m = v; }
                else       { s += __expf(v - m); }
            }
        }
    }
    __shared__ float smx[4], ssx[4];
    if (lane == 0) { smx[wid] = m; ssx[wid] = s; }
    __syncthreads();
    if (tid == 0) {
        float M = -INFINITY, S = 0.0f;
#pragma unroll
        for (int w = 0; w < 4; ++w) {
            float mb = smx[w], sb = ssx[w];
            if (sb > 0.0f) {
                if (mb > M) { S = S * __expf(M - mb) + sb; M = mb; }
                else        { S += sb * __expf(mb - M); }
            }
        }
        ws[WSF_PM + blockIdx.x] = M;
        ws[WSF_PS + blockIdx.x] = S;
    }
}

// =====================================================================
// K6: redundant deterministic LSE + write log-probs.  197 blocks x 256
// =====================================================================
__global__ __launch_bounds__(256) void k_outlse(
    const float* __restrict__ ws, float* __restrict__ out)
{
    __shared__ float smx[256], ssx[256];
    const int tid = threadIdx.x;
    float M = -INFINITY, S = 0.0f;
    for (int i = tid; i < NBLK_V; i += 256) {
        float mb = ws[WSF_PM + i], sb = ws[WSF_PS + i];
        if (mb > M) { S = S * __expf(M - mb) + sb; M = mb; }
        else        { S += sb * __expf(mb - M); }
    }
    smx[tid] = M; ssx[tid] = S;
    __syncthreads();
    for (int st = 128; st > 0; st >>= 1) {
        if (tid < st) {
            float mb = smx[tid + st], sb = ssx[tid + st];
            if (sb > 0.0f) {
                if (mb > smx[tid]) { ssx[tid] = ssx[tid] * __expf(smx[tid] - mb) + sb; smx[tid] = mb; }
                else               { ssx[tid] += sb * __expf(mb - smx[tid]); }
            }
        }
        __syncthreads();
    }
    const float lse = smx[0] + logf(ssx[0]);
    const int i = blockIdx.x * 256 + tid;
    if (i < NVOCAB) out[i] = ws[WSF_LOGV + i] - lse;
}

// =====================================================================
extern "C" void kernel_launch(void* const* d_in, const int* in_sizes, int n_in,
                              void* d_out, int out_size, void* d_ws, size_t ws_size,
                              hipStream_t stream)
{
    (void)in_sizes; (void)n_in; (void)out_size; (void)ws_size;
    const float* emb     = (const float*)d_in[0];
    const float* conv1_w = (const float*)d_in[1];  const float* conv1_b = (const float*)d_in[2];
    const float* conv2_w = (const float*)d_in[3];  const float* conv2_b = (const float*)d_in[4];
    const float* conv3_w = (const float*)d_in[5];  const float* conv3_b = (const float*)d_in[6];
    const float* conv4_w = (const float*)d_in[7];  const float* conv4_b = (const float*)d_in[8];
    const float* conv5_w = (const float*)d_in[9];  const float* conv5_b = (const float*)d_in[10];
    const float* conv6_w = (const float*)d_in[11]; const float* conv6_b = (const float*)d_in[12];
    const float* bn1_g = (const float*)d_in[13];   const float* bn1_b = (const float*)d_in[14];
    const float* bn2_g = (const float*)d_in[15];   const float* bn2_b = (const float*)d_in[16];
    const float* bn3_g = (const float*)d_in[17];   const float* bn3_b = (const float*)d_in[18];
    const float* bn4_g = (const float*)d_in[19];   const float* bn4_b = (const float*)d_in[20];
    const float* bn5_g = (const float*)d_in[21];   const float* bn5_b = (const float*)d_in[22];
    const float* bn6_g = (const float*)d_in[23];   const float* bn6_b = (const float*)d_in[24];
    const float* att_w = (const float*)d_in[25];   const float* att_b = (const float*)d_in[26];
    const float* gru_wih = (const float*)d_in[27]; const float* gru_whh = (const float*)d_in[28];
    const float* gru_bih = (const float*)d_in[29]; const float* gru_bhh = (const float*)d_in[30];
    const float* lo_w = (const float*)d_in[31];    const float* lo_b = (const float*)d_in[32];
    const float* h_state = (const float*)d_in[33];
    const float* enc = (const float*)d_in[34];
    const int* x = (const int*)d_in[35];

    float* ws = (float*)d_ws;
    float* out = (float*)d_out;

    k_pre<<<1, 512, 0, stream>>>(emb, x, h_state,
        conv1_w, conv1_b, conv2_w, conv2_b, conv3_w, conv3_b,
        bn1_g, bn1_b, bn2_g, bn2_b, bn3_g, bn3_b, ws);
    k_att<<<256, 256, 0, stream>>>(att_w, att_b, enc, gru_whh, gru_bhh, h_state, ws);
    k_post<<<1, 512, 0, stream>>>(emb, x,
        conv4_w, conv4_b, conv5_w, conv5_b, conv6_w, conv6_b,
        bn4_g, bn4_b, bn5_g, bn5_b, bn6_g, bn6_b, ws);
    for (int l = 0; l < 4; ++l) {
        k_grux<<<128, 256, 0, stream>>>(gru_wih, gru_bih, h_state,
            ws + WSF_XT + l * 512, ws + WSF_XT + (l + 1) * 512,
            out + NVOCAB + l * 512, ws + WSF_GH + l * 1536, l);
    }
    k_vocab<<<NBLK_V, 256, 0, stream>>>(lo_w, lo_b, ws);
    k_outlse<<<197, 256, 0, stream>>>(ws, out);
}

// Round 11
// 100.270 us; speedup vs baseline: 2.9779x; 1.0086x over previous
//
#include <hip/hip_runtime.h>
#include <hip/hip_bf16.h>

typedef __attribute__((ext_vector_type(4))) float f32x4;

// ---------------- workspace layout (fp32 elements) ----------------
constexpr int WSF_ADEN  = 512;      // 64     per-chunk exp-sum
constexpr int WSF_APART = 1024;     // 64*1024 per-chunk PV partials (unnormalized)
constexpr int WSF_XT    = 66560;    // 5*512  xt chain (slot 0 unused; layers write 1..4)
constexpr int WSF_LOGV  = 69120;    // 50257  vocab logits
constexpr int WSF_PM    = 119424;   // 786    per-block max
constexpr int WSF_PS    = 120320;   // 786    per-block sum-exp
constexpr int NVOCAB    = 50257;
constexpr int NBLK_V    = 786;      // ceil(50257/64)

__device__ __forceinline__ float wave_rsum(float v) {
#pragma unroll
    for (int o = 32; o > 0; o >>= 1) v += __shfl_down(v, o);
    return v; // lane 0 holds sum
}
__device__ __forceinline__ float sigm(float x) { return 1.0f / (1.0f + __expf(-x)); }

// =====================================================================
// K1: REDUNDANT pre-conv stack (every block, identical => deterministic)
// + attention chunk.  64 blocks x 256 threads.
// Conv code = R5-verified 256-thread version; attention = R6-verified.
// =====================================================================
__global__ __launch_bounds__(256) void k_preatt(
    const float* __restrict__ emb, const int* __restrict__ xidx,
    const float* __restrict__ hstate,
    const float* __restrict__ w1, const float* __restrict__ b1,
    const float* __restrict__ w2, const float* __restrict__ b2,
    const float* __restrict__ w3, const float* __restrict__ b3,
    const float* __restrict__ g1, const float* __restrict__ bb1,
    const float* __restrict__ g2, const float* __restrict__ bb2,
    const float* __restrict__ g3, const float* __restrict__ bb3,
    const float* __restrict__ attw, const float* __restrict__ attb,
    const float* __restrict__ enc, float* __restrict__ ws)
{
    __shared__ float s_w[1089];
    __shared__ float s_pre[5][512];
    __shared__ float s_y[32][512];
    __shared__ float s_stat[32][2];
    __shared__ float s_q[512];
    __shared__ float s_e[32];
    __shared__ float s_d[4];
    const int tid = threadIdx.x, lane = tid & 63, wid = tid >> 6;
    const int bid = blockIdx.x;

    // ---- stage conv1-3 params ----
    for (int i = tid; i < 480; i += 256) { s_w[i] = w1[i]; s_w[576 + i] = w2[i]; }
    if (tid < 32) { s_w[480+tid] = b1[tid]; s_w[512+tid] = g1[tid]; s_w[544+tid] = bb1[tid]; }
    if (tid < 5)  { s_w[1056+tid] = b2[tid]; s_w[1061+tid] = g2[tid]; s_w[1066+tid] = bb2[tid]; }
    if (tid < 15) s_w[1071+tid] = w3[tid];
    if (tid == 0) { s_w[1086] = b3[0]; s_w[1087] = g3[0]; s_w[1088] = bb3[0]; }
    const int x = xidx[0];
#pragma unroll
    for (int c = 0; c < 4; ++c) {
        s_pre[c][tid]       = hstate[c*512 + tid];
        s_pre[c][tid + 256] = hstate[c*512 + 256 + tid];
    }
    s_pre[4][tid]       = emb[(size_t)x*512 + tid];
    s_pre[4][tid + 256] = emb[(size_t)x*512 + 256 + tid];
    __syncthreads();

    // ---- conv1 (5->32), pre-BN into s_y ----
#pragma unroll
    for (int pp = 0; pp < 2; ++pp) {
        const int l = tid + pp * 256;
        float px[5][3];
#pragma unroll
        for (int ic = 0; ic < 5; ++ic) {
            px[ic][0] = (l > 0)   ? s_pre[ic][l-1] : 0.f;
            px[ic][1] =             s_pre[ic][l];
            px[ic][2] = (l < 511) ? s_pre[ic][l+1] : 0.f;
        }
#pragma unroll 4
        for (int oc = 0; oc < 32; ++oc) {
            float a = s_w[480 + oc];
#pragma unroll
            for (int ic = 0; ic < 5; ++ic)
#pragma unroll
                for (int k = 0; k < 3; ++k)
                    a += s_w[oc*15 + ic*3 + k] * px[ic][k];
            s_y[oc][l] = a;
        }
    }
    __syncthreads();
    // ---- BN1 stats: 4 waves x 8 channels ----
#pragma unroll
    for (int t = 0; t < 8; ++t) {
        const int oc = wid * 8 + t;
        float s = 0.f, s2 = 0.f;
#pragma unroll
        for (int j = 0; j < 8; ++j) { float v = s_y[oc][lane + j*64]; s += v; s2 += v*v; }
        s = wave_rsum(s); s2 = wave_rsum(s2);
        if (lane == 0) {
            float m = s * (1.f/512.f), var = s2 * (1.f/512.f) - m*m;
            s_stat[oc][0] = m; s_stat[oc][1] = rsqrtf(var + 1e-5f);
        }
    }
    __syncthreads();
#pragma unroll
    for (int pp = 0; pp < 2; ++pp) {
        const int l = tid + pp * 256;
#pragma unroll 4
        for (int oc = 0; oc < 32; ++oc) {
            float m = s_stat[oc][0], r = s_stat[oc][1];
            s_y[oc][l] = fmaxf((s_y[oc][l] - m) * r * s_w[512+oc] + s_w[544+oc], 0.f);
        }
    }
    __syncthreads();

    // ---- conv2 (32->5) + residual ----
    float y2[2][5];
#pragma unroll
    for (int pp = 0; pp < 2; ++pp)
#pragma unroll
        for (int oc = 0; oc < 5; ++oc) y2[pp][oc] = s_w[1056 + oc];
#pragma unroll 2
    for (int ic = 0; ic < 32; ++ic) {
#pragma unroll
        for (int pp = 0; pp < 2; ++pp) {
            const int l = tid + pp * 256;
            float c0 = (l > 0)   ? s_y[ic][l-1] : 0.f;
            float c1 =             s_y[ic][l];
            float c2 = (l < 511) ? s_y[ic][l+1] : 0.f;
#pragma unroll
            for (int oc = 0; oc < 5; ++oc) {
                const int base = 576 + (oc*32 + ic)*3;
                y2[pp][oc] += s_w[base]*c0 + s_w[base+1]*c1 + s_w[base+2]*c2;
            }
        }
    }
#pragma unroll
    for (int pp = 0; pp < 2; ++pp) {
        const int l = tid + pp * 256;
#pragma unroll
        for (int oc = 0; oc < 5; ++oc) y2[pp][oc] += s_pre[oc][l];
    }
    __syncthreads();
#pragma unroll
    for (int pp = 0; pp < 2; ++pp) {
        const int l = tid + pp * 256;
#pragma unroll
        for (int oc = 0; oc < 5; ++oc) s_y[oc][l] = y2[pp][oc];
    }
    __syncthreads();
#pragma unroll
    for (int t = 0; t < 2; ++t) {
        const int oc = wid + 4 * t;
        if (oc < 5) {
            float s = 0.f, s2 = 0.f;
#pragma unroll
            for (int j = 0; j < 8; ++j) { float v = s_y[oc][lane + j*64]; s += v; s2 += v*v; }
            s = wave_rsum(s); s2 = wave_rsum(s2);
            if (lane == 0) {
                float m = s * (1.f/512.f), var = s2 * (1.f/512.f) - m*m;
                s_stat[oc][0] = m; s_stat[oc][1] = rsqrtf(var + 1e-5f);
            }
        }
    }
    __syncthreads();
#pragma unroll
    for (int pp = 0; pp < 2; ++pp) {
        const int l = tid + pp * 256;
#pragma unroll
        for (int oc = 0; oc < 5; ++oc) {
            float m = s_stat[oc][0], r = s_stat[oc][1];
            s_pre[oc][l] = fmaxf((y2[pp][oc] - m) * r * s_w[1061+oc] + s_w[1066+oc], 0.f);
        }
    }
    __syncthreads();

    // ---- conv3 (5->1) ----
    float a3[2];
#pragma unroll
    for (int pp = 0; pp < 2; ++pp) {
        const int l = tid + pp * 256;
        float a = s_w[1086];
#pragma unroll
        for (int ic = 0; ic < 5; ++ic) {
            float c0 = (l > 0)   ? s_pre[ic][l-1] : 0.f;
            float c1 =             s_pre[ic][l];
            float c2 = (l < 511) ? s_pre[ic][l+1] : 0.f;
            a += s_w[1071+ic*3]*c0 + s_w[1071+ic*3+1]*c1 + s_w[1071+ic*3+2]*c2;
        }
        a3[pp] = a;
        s_y[0][l] = a;
    }
    __syncthreads();
    if (wid == 0) {
        float s = 0.f, s2 = 0.f;
#pragma unroll
        for (int j = 0; j < 8; ++j) { float v = s_y[0][lane + j*64]; s += v; s2 += v*v; }
        s = wave_rsum(s); s2 = wave_rsum(s2);
        if (lane == 0) {
            float m = s * (1.f/512.f), var = s2 * (1.f/512.f) - m*m;
            s_stat[0][0] = m; s_stat[0][1] = rsqrtf(var + 1e-5f);
        }
    }
    __syncthreads();
#pragma unroll
    for (int pp = 0; pp < 2; ++pp) {
        const int l = tid + pp * 256;
        s_q[l] = fmaxf((a3[pp] - s_stat[0][0]) * s_stat[0][1] * s_w[1087] + s_w[1088], 0.f);
    }
    __syncthreads();

    // ---- attention chunk jc = bid (R6-proven; q from LDS) ----
    const int jc = bid;
    float q0[4], q1[4];
#pragma unroll
    for (int j = 0; j < 4; ++j) {
        q0[j] = s_q[lane*4 + j];
        q1[j] = s_q[256 + lane*4 + j];
    }
    float dpart = 0.f;
#pragma unroll 4
    for (int r = 0; r < 8; ++r) {
        const int row = jc * 32 + wid * 8 + r;
        f32x4 w0 = *(const f32x4*)(attw + (size_t)row*512 + lane*4);
        f32x4 w1v = *(const f32x4*)(attw + (size_t)row*512 + 256 + lane*4);
        float a = 0.f;
#pragma unroll
        for (int j = 0; j < 4; ++j) a += w0[j]*q0[j] + w1v[j]*q1[j];
        a = wave_rsum(a);
        if (lane == 0) {
            float e = __expf(a + attb[row]);   // |logit| << 80: exp-safe (R5/R6)
            s_e[wid*8 + r] = e;
            dpart += e;
        }
    }
    if (lane == 0) s_d[wid] = dpart;
    __syncthreads();
    if (tid == 0) ws[WSF_ADEN + jc] = s_d[0] + s_d[1] + s_d[2] + s_d[3];

    const int col = tid * 4;
    const float* ep = enc + (size_t)(jc * 32) * 1024 + col;
    f32x4 acc = {0.f, 0.f, 0.f, 0.f};
#pragma unroll 8
    for (int jj = 0; jj < 32; ++jj) {
        f32x4 v = *(const f32x4*)(ep + (size_t)jj * 1024);
        acc += s_e[jj] * v;
    }
    *(f32x4*)(ws + WSF_APART + jc * 1024 + col) = acc;
}

// =====================================================================
// K2: REDUNDANT post-conv stack (every block) + GRU layer 0 for the
// block's 8 units.  64 blocks x 256 threads.
// =====================================================================
__global__ __launch_bounds__(256) void k_postgru(
    const float* __restrict__ emb, const int* __restrict__ xidx,
    const float* __restrict__ w4, const float* __restrict__ b4,
    const float* __restrict__ w5, const float* __restrict__ b5,
    const float* __restrict__ w6, const float* __restrict__ b6,
    const float* __restrict__ g4, const float* __restrict__ bb4,
    const float* __restrict__ g5, const float* __restrict__ bb5,
    const float* __restrict__ g6, const float* __restrict__ bb6,
    const float* __restrict__ wih, const float* __restrict__ whh,
    const float* __restrict__ bih, const float* __restrict__ bhh,
    const float* __restrict__ hstate,
    float* __restrict__ ws, float* __restrict__ out)
{
    __shared__ float s_w[693];
    __shared__ float s_com[3][512];
    __shared__ float s_y[32][512];
    __shared__ float s_stat[32][2];
    __shared__ float s_xt[512];
    __shared__ float s_g[8][6];
    const int tid = threadIdx.x, lane = tid & 63, wid = tid >> 6;
    const int bid = blockIdx.x;

    for (int i = tid; i < 288; i += 256) { s_w[i] = w4[i]; s_w[384 + i] = w5[i]; }
    if (tid < 32) { s_w[288+tid] = b4[tid]; s_w[320+tid] = g4[tid]; s_w[352+tid] = bb4[tid]; }
    if (tid < 3)  { s_w[672+tid] = b5[tid]; s_w[675+tid] = g5[tid]; s_w[678+tid] = bb5[tid]; }
    if (tid < 9)  s_w[681+tid] = w6[tid];
    if (tid == 0) { s_w[690] = b6[0]; s_w[691] = g6[0]; s_w[692] = bb6[0]; }

    // den + app from the 64 attention chunk partials
    float den = 0.f;
#pragma unroll 8
    for (int i = 0; i < 64; ++i) den += ws[WSF_ADEN + i];
    const float invS = 1.0f / den;
    const int x = xidx[0];
#pragma unroll
    for (int pp = 0; pp < 2; ++pp) {
        const int l = tid + pp * 256;
        float a0 = 0.f, a1 = 0.f;
#pragma unroll 8
        for (int p = 0; p < 64; ++p) {
            a0 += ws[WSF_APART + p*1024 + l];
            a1 += ws[WSF_APART + p*1024 + 512 + l];
        }
        s_com[0][l] = a0 * invS;
        s_com[1][l] = a1 * invS;
        s_com[2][l] = emb[(size_t)x*512 + l];
    }
    __syncthreads();

    // ---- conv4 (3->32) ----
#pragma unroll
    for (int pp = 0; pp < 2; ++pp) {
        const int l = tid + pp * 256;
        float px[3][3];
#pragma unroll
        for (int ic = 0; ic < 3; ++ic) {
            px[ic][0] = (l > 0)   ? s_com[ic][l-1] : 0.f;
            px[ic][1] =             s_com[ic][l];
            px[ic][2] = (l < 511) ? s_com[ic][l+1] : 0.f;
        }
#pragma unroll 4
        for (int oc = 0; oc < 32; ++oc) {
            float a = s_w[288 + oc];
#pragma unroll
            for (int ic = 0; ic < 3; ++ic)
#pragma unroll
                for (int k = 0; k < 3; ++k)
                    a += s_w[oc*9 + ic*3 + k] * px[ic][k];
            s_y[oc][l] = a;
        }
    }
    __syncthreads();
#pragma unroll
    for (int t = 0; t < 8; ++t) {
        const int oc = wid * 8 + t;
        float s = 0.f, s2 = 0.f;
#pragma unroll
        for (int j = 0; j < 8; ++j) { float v = s_y[oc][lane + j*64]; s += v; s2 += v*v; }
        s = wave_rsum(s); s2 = wave_rsum(s2);
        if (lane == 0) {
            float m = s * (1.f/512.f), var = s2 * (1.f/512.f) - m*m;
            s_stat[oc][0] = m; s_stat[oc][1] = rsqrtf(var + 1e-5f);
        }
    }
    __syncthreads();
#pragma unroll
    for (int pp = 0; pp < 2; ++pp) {
        const int l = tid + pp * 256;
#pragma unroll 4
        for (int oc = 0; oc < 32; ++oc) {
            float m = s_stat[oc][0], r = s_stat[oc][1];
            s_y[oc][l] = fmaxf((s_y[oc][l] - m) * r * s_w[320+oc] + s_w[352+oc], 0.f);
        }
    }
    __syncthreads();

    // ---- conv5 (32->3) + residual ----
    float y2[2][3];
#pragma unroll
    for (int pp = 0; pp < 2; ++pp)
#pragma unroll
        for (int oc = 0; oc < 3; ++oc) y2[pp][oc] = s_w[672 + oc];
#pragma unroll 2
    for (int ic = 0; ic < 32; ++ic) {
#pragma unroll
        for (int pp = 0; pp < 2; ++pp) {
            const int l = tid + pp * 256;
            float c0 = (l > 0)   ? s_y[ic][l-1] : 0.f;
            float c1 =             s_y[ic][l];
            float c2 = (l < 511) ? s_y[ic][l+1] : 0.f;
#pragma unroll
            for (int oc = 0; oc < 3; ++oc) {
                const int base = 384 + (oc*32 + ic)*3;
                y2[pp][oc] += s_w[base]*c0 + s_w[base+1]*c1 + s_w[base+2]*c2;
            }
        }
    }
#pragma unroll
    for (int pp = 0; pp < 2; ++pp) {
        const int l = tid + pp * 256;
#pragma unroll
        for (int oc = 0; oc < 3; ++oc) y2[pp][oc] += s_com[oc][l];
    }
    __syncthreads();
#pragma unroll
    for (int pp = 0; pp < 2; ++pp) {
        const int l = tid + pp * 256;
#pragma unroll
        for (int oc = 0; oc < 3; ++oc) s_y[oc][l] = y2[pp][oc];
    }
    __syncthreads();
    if (wid < 3) {
        const int oc = wid;
        float s = 0.f, s2 = 0.f;
#pragma unroll
        for (int j = 0; j < 8; ++j) { float v = s_y[oc][lane + j*64]; s += v; s2 += v*v; }
        s = wave_rsum(s); s2 = wave_rsum(s2);
        if (lane == 0) {
            float m = s * (1.f/512.f), var = s2 * (1.f/512.f) - m*m;
            s_stat[oc][0] = m; s_stat[oc][1] = rsqrtf(var + 1e-5f);
        }
    }
    __syncthreads();
#pragma unroll
    for (int pp = 0; pp < 2; ++pp) {
        const int l = tid + pp * 256;
#pragma unroll
        for (int oc = 0; oc < 3; ++oc) {
            float m = s_stat[oc][0], r = s_stat[oc][1];
            s_com[oc][l] = fmaxf((y2[pp][oc] - m) * r * s_w[675+oc] + s_w[678+oc], 0.f);
        }
    }
    __syncthreads();

    // ---- conv6 (3->1) ----
    float a6[2];
#pragma unroll
    for (int pp = 0; pp < 2; ++pp) {
        const int l = tid + pp * 256;
        float a = s_w[690];
#pragma unroll
        for (int ic = 0; ic < 3; ++ic) {
            float c0 = (l > 0)   ? s_com[ic][l-1] : 0.f;
            float c1 =             s_com[ic][l];
            float c2 = (l < 511) ? s_com[ic][l+1] : 0.f;
            a += s_w[681+ic*3]*c0 + s_w[681+ic*3+1]*c1 + s_w[681+ic*3+2]*c2;
        }
        a6[pp] = a;
        s_y[0][l] = a;
    }
    __syncthreads();
    if (wid == 0) {
        float s = 0.f, s2 = 0.f;
#pragma unroll
        for (int j = 0; j < 8; ++j) { float v = s_y[0][lane + j*64]; s += v; s2 += v*v; }
        s = wave_rsum(s); s2 = wave_rsum(s2);
        if (lane == 0) {
            float m = s * (1.f/512.f), var = s2 * (1.f/512.f) - m*m;
            s_stat[0][0] = m; s_stat[0][1] = rsqrtf(var + 1e-5f);
        }
    }
    __syncthreads();
#pragma unroll
    for (int pp = 0; pp < 2; ++pp) {
        const int l = tid + pp * 256;
        s_xt[l] = fmaxf((a6[pp] - s_stat[0][0]) * s_stat[0][1] * s_w[691] + s_w[692], 0.f);
    }
    __syncthreads();

    // ---- GRU layer 0 for this block's 8 units (R6-proven body; xt from LDS) ----
    const float* hp = hstate;
    const int i0 = bid * 8;
    float xq0[4], xq1[4], hq0[4], hq1[4];
#pragma unroll
    for (int j = 0; j < 4; ++j) {
        xq0[j] = s_xt[lane*4 + j];
        xq1[j] = s_xt[256 + lane*4 + j];
        hq0[j] = hp[lane*4 + j];
        hq1[j] = hp[256 + lane*4 + j];
    }
#pragma unroll
    for (int t = 0; t < 2; ++t) {
        const int ii = wid * 2 + t;
        const int i = i0 + ii;
        float a[6] = {0.f, 0.f, 0.f, 0.f, 0.f, 0.f};
#pragma unroll
        for (int g = 0; g < 3; ++g) {
            const float* wr = wih + (size_t)(i + g*512) * 512;
            f32x4 w0 = *(const f32x4*)(wr + lane*4);
            f32x4 w1v = *(const f32x4*)(wr + 256 + lane*4);
#pragma unroll
            for (int j = 0; j < 4; ++j) a[g] += w0[j]*xq0[j] + w1v[j]*xq1[j];
        }
#pragma unroll
        for (int g = 0; g < 3; ++g) {
            const float* wr = whh + (size_t)(i + g*512) * 512;
            f32x4 w0 = *(const f32x4*)(wr + lane*4);
            f32x4 w1v = *(const f32x4*)(wr + 256 + lane*4);
#pragma unroll
            for (int j = 0; j < 4; ++j) a[3+g] += w0[j]*hq0[j] + w1v[j]*hq1[j];
        }
#pragma unroll
        for (int g = 0; g < 6; ++g) a[g] = wave_rsum(a[g]);
        if (lane == 0) {
#pragma unroll
            for (int g = 0; g < 6; ++g) s_g[ii][g] = a[g];
        }
    }
    __syncthreads();
    if (tid < 8) {
        const int i = i0 + tid;
        float ir = s_g[tid][0] + bih[i];
        float iz = s_g[tid][1] + bih[i + 512];
        float in_ = s_g[tid][2] + bih[i + 1024];
        float hr = s_g[tid][3] + bhh[i];
        float hz = s_g[tid][4] + bhh[i + 512];
        float hn = s_g[tid][5] + bhh[i + 1024];
        float r = sigm(ir + hr);
        float z = sigm(iz + hz);
        float n = tanhf(in_ + r * hn);
        float h = (1.f - z) * n + z * hp[i];
        ws[WSF_XT + 512 + i] = h;     // layer-1 input
        out[NVOCAB + i] = h;          // h_new layer 0
    }
}

// =====================================================================
// K3: one GRU layer (layers 1..3; R6-proven).  64 blocks x 256.
// =====================================================================
__global__ __launch_bounds__(256) void k_gru(
    const float* __restrict__ wih, const float* __restrict__ whh,
    const float* __restrict__ bih, const float* __restrict__ bhh,
    const float* __restrict__ hstate,
    const float* __restrict__ xt_in, float* __restrict__ xt_out,
    float* __restrict__ hout, int layer)
{
    wih += (size_t)layer * 1536 * 512;
    whh += (size_t)layer * 1536 * 512;
    bih += layer * 1536;
    bhh += layer * 1536;
    const float* hp = hstate + layer * 512;

    const int tid = threadIdx.x, lane = tid & 63, wid = tid >> 6;
    float xq0[4], xq1[4], hq0[4], hq1[4];
#pragma unroll
    for (int j = 0; j < 4; ++j) {
        xq0[j] = xt_in[lane*4 + j];
        xq1[j] = xt_in[256 + lane*4 + j];
        hq0[j] = hp[lane*4 + j];
        hq1[j] = hp[256 + lane*4 + j];
    }
    __shared__ float s_g[8][6];
    const int i0 = blockIdx.x * 8;
#pragma unroll
    for (int t = 0; t < 2; ++t) {
        const int ii = wid * 2 + t;
        const int i = i0 + ii;
        float a[6] = {0.f, 0.f, 0.f, 0.f, 0.f, 0.f};
#pragma unroll
        for (int g = 0; g < 3; ++g) {
            const float* wr = wih + (size_t)(i + g*512) * 512;
            f32x4 w0 = *(const f32x4*)(wr + lane*4);
            f32x4 w1 = *(const f32x4*)(wr + 256 + lane*4);
#pragma unroll
            for (int j = 0; j < 4; ++j) a[g] += w0[j]*xq0[j] + w1[j]*xq1[j];
        }
#pragma unroll
        for (int g = 0; g < 3; ++g) {
            const float* wr = whh + (size_t)(i + g*512) * 512;
            f32x4 w0 = *(const f32x4*)(wr + lane*4);
            f32x4 w1 = *(const f32x4*)(wr + 256 + lane*4);
#pragma unroll
            for (int j = 0; j < 4; ++j) a[3+g] += w0[j]*hq0[j] + w1[j]*hq1[j];
        }
#pragma unroll
        for (int g = 0; g < 6; ++g) a[g] = wave_rsum(a[g]);
        if (lane == 0) {
#pragma unroll
            for (int g = 0; g < 6; ++g) s_g[ii][g] = a[g];
        }
    }
    __syncthreads();
    if (tid < 8) {
        const int i = i0 + tid;
        float ir = s_g[tid][0] + bih[i];
        float iz = s_g[tid][1] + bih[i + 512];
        float in_ = s_g[tid][2] + bih[i + 1024];
        float hr = s_g[tid][3] + bhh[i];
        float hz = s_g[tid][4] + bhh[i + 512];
        float hn = s_g[tid][5] + bhh[i + 1024];
        float r = sigm(ir + hr);
        float z = sigm(iz + hz);
        float n = tanhf(in_ + r * hn);
        float h = (1.f - z) * n + z * hp[i];
        xt_out[i] = h;
        hout[i] = h;
    }
}

// =====================================================================
// K4: vocab GEMV + per-block online (max, sum-exp).  786 x 256 (R6 exact)
// =====================================================================
__global__ __launch_bounds__(256) void k_vocab(
    const float* __restrict__ low, const float* __restrict__ lob,
    float* __restrict__ ws)
{
    const int tid = threadIdx.x, lane = tid & 63, wid = tid >> 6;
    float q0[4], q1[4];
#pragma unroll
    for (int j = 0; j < 4; ++j) {
        q0[j] = ws[WSF_XT + 4*512 + lane*4 + j];
        q1[j] = ws[WSF_XT + 4*512 + 256 + lane*4 + j];
    }
    const int row0 = blockIdx.x * 64 + wid * 16;
    float m = -INFINITY, s = 0.0f;
#pragma unroll 4
    for (int r = 0; r < 16; ++r) {
        const int row = row0 + r;
        if (row < NVOCAB) {
            f32x4 w0 = *(const f32x4*)(low + (size_t)row*512 + lane*4);
            f32x4 w1 = *(const f32x4*)(low + (size_t)row*512 + 256 + lane*4);
            float a = 0.f;
#pragma unroll
            for (int j = 0; j < 4; ++j) a += w0[j]*q0[j] + w1[j]*q1[j];
            a = wave_rsum(a);
            if (lane == 0) {
                float v = a + lob[row];
                ws[WSF_LOGV + row] = v;
                if (v > m) { s = s * __expf(m - v) + 1.0f; m = v; }
                else       { s += __expf(v - m); }
            }
        }
    }
    __shared__ float smx[4], ssx[4];
    if (lane == 0) { smx[wid] = m; ssx[wid] = s; }
    __syncthreads();
    if (tid == 0) {
        float M = -INFINITY, S = 0.0f;
#pragma unroll
        for (int w = 0; w < 4; ++w) {
            float mb = smx[w], sb = ssx[w];
            if (sb > 0.0f) {
                if (mb > M) { S = S * __expf(M - mb) + sb; M = mb; }
                else        { S += sb * __expf(mb - M); }
            }
        }
        ws[WSF_PM + blockIdx.x] = M;
        ws[WSF_PS + blockIdx.x] = S;
    }
}

// =====================================================================
// K5: redundant deterministic LSE + write log-probs.  197 blocks x 256
// =====================================================================
__global__ __launch_bounds__(256) void k_outlse(
    const float* __restrict__ ws, float* __restrict__ out)
{
    __shared__ float smx[256], ssx[256];
    const int tid = threadIdx.x;
    float M = -INFINITY, S = 0.0f;
    for (int i = tid; i < NBLK_V; i += 256) {
        float mb = ws[WSF_PM + i], sb = ws[WSF_PS + i];
        if (mb > M) { S = S * __expf(M - mb) + sb; M = mb; }
        else        { S += sb * __expf(mb - M); }
    }
    smx[tid] = M; ssx[tid] = S;
    __syncthreads();
    for (int st = 128; st > 0; st >>= 1) {
        if (tid < st) {
            float mb = smx[tid + st], sb = ssx[tid + st];
            if (sb > 0.0f) {
                if (mb > smx[tid]) { ssx[tid] = ssx[tid] * __expf(smx[tid] - mb) + sb; smx[tid] = mb; }
                else               { ssx[tid] += sb * __expf(mb - smx[tid]); }
            }
        }
        __syncthreads();
    }
    const float lse = smx[0] + logf(ssx[0]);
    const int i = blockIdx.x * 256 + tid;
    if (i < NVOCAB) out[i] = ws[WSF_LOGV + i] - lse;
}

// =====================================================================
extern "C" void kernel_launch(void* const* d_in, const int* in_sizes, int n_in,
                              void* d_out, int out_size, void* d_ws, size_t ws_size,
                              hipStream_t stream)
{
    (void)in_sizes; (void)n_in; (void)out_size; (void)ws_size;
    const float* emb     = (const float*)d_in[0];
    const float* conv1_w = (const float*)d_in[1];  const float* conv1_b = (const float*)d_in[2];
    const float* conv2_w = (const float*)d_in[3];  const float* conv2_b = (const float*)d_in[4];
    const float* conv3_w = (const float*)d_in[5];  const float* conv3_b = (const float*)d_in[6];
    const float* conv4_w = (const float*)d_in[7];  const float* conv4_b = (const float*)d_in[8];
    const float* conv5_w = (const float*)d_in[9];  const float* conv5_b = (const float*)d_in[10];
    const float* conv6_w = (const float*)d_in[11]; const float* conv6_b = (const float*)d_in[12];
    const float* bn1_g = (const float*)d_in[13];   const float* bn1_b = (const float*)d_in[14];
    const float* bn2_g = (const float*)d_in[15];   const float* bn2_b = (const float*)d_in[16];
    const float* bn3_g = (const float*)d_in[17];   const float* bn3_b = (const float*)d_in[18];
    const float* bn4_g = (const float*)d_in[19];   const float* bn4_b = (const float*)d_in[20];
    const float* bn5_g = (const float*)d_in[21];   const float* bn5_b = (const float*)d_in[22];
    const float* bn6_g = (const float*)d_in[23];   const float* bn6_b = (const float*)d_in[24];
    const float* att_w = (const float*)d_in[25];   const float* att_b = (const float*)d_in[26];
    const float* gru_wih = (const float*)d_in[27]; const float* gru_whh = (const float*)d_in[28];
    const float* gru_bih = (const float*)d_in[29]; const float* gru_bhh = (const float*)d_in[30];
    const float* lo_w = (const float*)d_in[31];    const float* lo_b = (const float*)d_in[32];
    const float* h_state = (const float*)d_in[33];
    const float* enc = (const float*)d_in[34];
    const int* x = (const int*)d_in[35];

    float* ws = (float*)d_ws;
    float* out = (float*)d_out;

    k_preatt<<<64, 256, 0, stream>>>(emb, x, h_state,
        conv1_w, conv1_b, conv2_w, conv2_b, conv3_w, conv3_b,
        bn1_g, bn1_b, bn2_g, bn2_b, bn3_g, bn3_b,
        att_w, att_b, enc, ws);
    k_postgru<<<64, 256, 0, stream>>>(emb, x,
        conv4_w, conv4_b, conv5_w, conv5_b, conv6_w, conv6_b,
        bn4_g, bn4_b, bn5_g, bn5_b, bn6_g, bn6_b,
        gru_wih, gru_whh, gru_bih, gru_bhh, h_state, ws, out);
    for (int l = 1; l < 4; ++l) {
        k_gru<<<64, 256, 0, stream>>>(gru_wih, gru_whh, gru_bih, gru_bhh, h_state,
            ws + WSF_XT + l * 512, ws + WSF_XT + (l + 1) * 512,
            out + NVOCAB + l * 512, l);
    }
    k_vocab<<<NBLK_V, 256, 0, stream>>>(lo_w, lo_b, ws);
    k_outlse<<<197, 256, 0, stream>>>(ws, out);
}

// Round 12
// 94.806 us; speedup vs baseline: 3.1496x; 1.0576x over previous
//
#include <hip/hip_runtime.h>
#include <hip/hip_bf16.h>

typedef __attribute__((ext_vector_type(4))) float f32x4;

// ---------------- workspace layout (fp32 elements) ----------------
constexpr int WSF_Q     = 0;        // 512     attention query (conv3 out)
constexpr int WSF_ADEN  = 512;      // 128     per-chunk exp-sum
constexpr int WSF_APART = 1024;     // 128*1024 per-chunk PV partials (unnormalized)
constexpr int WSF_XT    = 132096;   // 5*512   xt chain
constexpr int WSF_LOGV  = 134656;   // 50257   vocab logits
constexpr int WSF_PM    = 184960;   // 786     per-block max
constexpr int WSF_PS    = 185856;   // 786     per-block sum-exp
constexpr int NVOCAB    = 50257;
constexpr int NBLK_V    = 786;      // ceil(50257/64)

__device__ __forceinline__ float wave_rsum(float v) {
#pragma unroll
    for (int o = 32; o > 0; o >>= 1) v += __shfl_down(v, o);
    return v; // lane 0 holds sum
}
__device__ __forceinline__ float sigm(float x) { return 1.0f / (1.0f + __expf(-x)); }

// =====================================================================
// K1: pre-attention conv stack.  1 block x 512 threads (R6 verbatim)
// =====================================================================
__global__ __launch_bounds__(512) void k_pre(
    const float* __restrict__ emb, const int* __restrict__ xidx,
    const float* __restrict__ hstate,
    const float* __restrict__ w1, const float* __restrict__ b1,
    const float* __restrict__ w2, const float* __restrict__ b2,
    const float* __restrict__ w3, const float* __restrict__ b3,
    const float* __restrict__ g1, const float* __restrict__ bb1,
    const float* __restrict__ g2, const float* __restrict__ bb2,
    const float* __restrict__ g3, const float* __restrict__ bb3,
    float* __restrict__ ws)
{
    constexpr int W1 = 0, B1 = 480, G1 = 512, BB1 = 544;
    constexpr int W2 = 576, B2 = 1056, G2 = 1061, BB2 = 1066;
    constexpr int W3 = 1071, B3 = 1086, G3 = 1087, BB3 = 1088, NW = 1089;
    __shared__ float s_w[NW];
    __shared__ float s_pre[5][512];
    __shared__ float s_y[32][512];
    __shared__ float s_stat[32][2];
    const int tid = threadIdx.x, lane = tid & 63, wid = tid >> 6, l = tid;

    if (tid < 480) s_w[W1 + tid] = w1[tid];
    if (tid < 32) { s_w[B1 + tid] = b1[tid]; s_w[G1 + tid] = g1[tid]; s_w[BB1 + tid] = bb1[tid]; }
    if (tid < 480) s_w[W2 + tid] = w2[tid];
    if (tid < 5) { s_w[B2 + tid] = b2[tid]; s_w[G2 + tid] = g2[tid]; s_w[BB2 + tid] = bb2[tid]; }
    if (tid < 15) s_w[W3 + tid] = w3[tid];
    if (tid == 0) { s_w[B3] = b3[0]; s_w[G3] = g3[0]; s_w[BB3] = bb3[0]; }

    const int x = xidx[0];
#pragma unroll
    for (int c = 0; c < 4; ++c) s_pre[c][l] = hstate[c * 512 + l];
    s_pre[4][l] = emb[(size_t)x * 512 + l];
    __syncthreads();

    // ---- conv1 (5->32) ----
    float px[5][3];
#pragma unroll
    for (int ic = 0; ic < 5; ++ic) {
        px[ic][0] = (l > 0)   ? s_pre[ic][l-1] : 0.f;
        px[ic][1] =             s_pre[ic][l];
        px[ic][2] = (l < 511) ? s_pre[ic][l+1] : 0.f;
    }
#pragma unroll 4
    for (int oc = 0; oc < 32; ++oc) {
        float a = s_w[B1 + oc];
#pragma unroll
        for (int ic = 0; ic < 5; ++ic)
#pragma unroll
            for (int k = 0; k < 3; ++k)
                a += s_w[W1 + oc*15 + ic*3 + k] * px[ic][k];
        s_y[oc][l] = a;
    }
    __syncthreads();
#pragma unroll
    for (int t = 0; t < 4; ++t) {
        const int oc = wid * 4 + t;
        float s = 0.f, s2 = 0.f;
#pragma unroll
        for (int j = 0; j < 8; ++j) { float v = s_y[oc][lane + j*64]; s += v; s2 += v*v; }
        s = wave_rsum(s); s2 = wave_rsum(s2);
        if (lane == 0) { float m = s/512.f, var = s2/512.f - m*m; s_stat[oc][0] = m; s_stat[oc][1] = rsqrtf(var + 1e-5f); }
    }
    __syncthreads();
#pragma unroll 4
    for (int oc = 0; oc < 32; ++oc)
        s_y[oc][l] = fmaxf((s_y[oc][l] - s_stat[oc][0]) * s_stat[oc][1] * s_w[G1+oc] + s_w[BB1+oc], 0.f);
    __syncthreads();

    // ---- conv2 (32->5) + residual ----
    float y2[5];
#pragma unroll
    for (int oc = 0; oc < 5; ++oc) y2[oc] = s_w[B2 + oc];
#pragma unroll 2
    for (int ic = 0; ic < 32; ++ic) {
        float c0 = (l > 0)   ? s_y[ic][l-1] : 0.f;
        float c1 =             s_y[ic][l];
        float c2 = (l < 511) ? s_y[ic][l+1] : 0.f;
#pragma unroll
        for (int oc = 0; oc < 5; ++oc) {
            const int base = W2 + (oc*32 + ic)*3;
            y2[oc] += s_w[base]*c0 + s_w[base+1]*c1 + s_w[base+2]*c2;
        }
    }
#pragma unroll
    for (int oc = 0; oc < 5; ++oc) y2[oc] += s_pre[oc][l];
    __syncthreads();
#pragma unroll
    for (int oc = 0; oc < 5; ++oc) s_y[oc][l] = y2[oc];
    __syncthreads();
    if (wid < 5) {
        const int oc = wid;
        float s = 0.f, s2 = 0.f;
#pragma unroll
        for (int j = 0; j < 8; ++j) { float v = s_y[oc][lane + j*64]; s += v; s2 += v*v; }
        s = wave_rsum(s); s2 = wave_rsum(s2);
        if (lane == 0) { float m = s/512.f, var = s2/512.f - m*m; s_stat[oc][0] = m; s_stat[oc][1] = rsqrtf(var + 1e-5f); }
    }
    __syncthreads();
#pragma unroll
    for (int oc = 0; oc < 5; ++oc)
        s_pre[oc][l] = fmaxf((y2[oc] - s_stat[oc][0]) * s_stat[oc][1] * s_w[G2+oc] + s_w[BB2+oc], 0.f);
    __syncthreads();

    // ---- conv3 (5->1) ----
    float a3 = s_w[B3];
#pragma unroll
    for (int ic = 0; ic < 5; ++ic) {
        float c0 = (l > 0)   ? s_pre[ic][l-1] : 0.f;
        float c1 =             s_pre[ic][l];
        float c2 = (l < 511) ? s_pre[ic][l+1] : 0.f;
        a3 += s_w[W3+ic*3]*c0 + s_w[W3+ic*3+1]*c1 + s_w[W3+ic*3+2]*c2;
    }
    s_y[0][l] = a3;
    __syncthreads();
    if (wid == 0) {
        float s = 0.f, s2 = 0.f;
#pragma unroll
        for (int j = 0; j < 8; ++j) { float v = s_y[0][lane + j*64]; s += v; s2 += v*v; }
        s = wave_rsum(s); s2 = wave_rsum(s2);
        if (lane == 0) { float m = s/512.f, var = s2/512.f - m*m; s_stat[0][0] = m; s_stat[0][1] = rsqrtf(var + 1e-5f); }
    }
    __syncthreads();
    ws[WSF_Q + l] = fmaxf((a3 - s_stat[0][0]) * s_stat[0][1] * s_w[G3] + s_w[BB3], 0.f);
}

// =====================================================================
// K2: fused attention, WIDENED to 128 blocks x 256.  Block jc: 16 logit
// rows, exp (no max; |logit|<~2, R5/R6-validated), partial denom, PV.
// =====================================================================
__global__ __launch_bounds__(256) void k_att(
    const float* __restrict__ attw, const float* __restrict__ attb,
    const float* __restrict__ enc, float* __restrict__ ws)
{
    __shared__ float s_e[16];
    __shared__ float s_d[4];
    const int tid = threadIdx.x, lane = tid & 63, wid = tid >> 6;
    const int jc = blockIdx.x;

    float q0[4], q1[4];
#pragma unroll
    for (int j = 0; j < 4; ++j) {
        q0[j] = ws[WSF_Q + lane*4 + j];
        q1[j] = ws[WSF_Q + 256 + lane*4 + j];
    }
    float dpart = 0.f;
#pragma unroll
    for (int r = 0; r < 4; ++r) {
        const int row = jc * 16 + wid * 4 + r;
        f32x4 w0 = *(const f32x4*)(attw + (size_t)row*512 + lane*4);
        f32x4 w1 = *(const f32x4*)(attw + (size_t)row*512 + 256 + lane*4);
        float a = 0.f;
#pragma unroll
        for (int j = 0; j < 4; ++j) a += w0[j]*q0[j] + w1[j]*q1[j];
        a = wave_rsum(a);
        if (lane == 0) {
            float e = __expf(a + attb[row]);
            s_e[wid*4 + r] = e;
            dpart += e;
        }
    }
    if (lane == 0) s_d[wid] = dpart;
    __syncthreads();
    if (tid == 0) ws[WSF_ADEN + jc] = s_d[0] + s_d[1] + s_d[2] + s_d[3];

    const int col = tid * 4;
    const float* ep = enc + (size_t)(jc * 16) * 1024 + col;
    f32x4 acc = {0.f, 0.f, 0.f, 0.f};
#pragma unroll 8
    for (int jj = 0; jj < 16; ++jj) {
        f32x4 v = *(const f32x4*)(ep + (size_t)jj * 1024);
        acc += s_e[jj] * v;
    }
    *(f32x4*)(ws + WSF_APART + jc * 1024 + col) = acc;
}

// =====================================================================
// K3: post-attention conv stack.  1 block x 512 (R6 body; 128 partials)
// =====================================================================
__global__ __launch_bounds__(512) void k_post(
    const float* __restrict__ emb, const int* __restrict__ xidx,
    const float* __restrict__ w4, const float* __restrict__ b4,
    const float* __restrict__ w5, const float* __restrict__ b5,
    const float* __restrict__ w6, const float* __restrict__ b6,
    const float* __restrict__ g4, const float* __restrict__ bb4,
    const float* __restrict__ g5, const float* __restrict__ bb5,
    const float* __restrict__ g6, const float* __restrict__ bb6,
    float* __restrict__ ws)
{
    constexpr int W4 = 0, B4 = 288, G4 = 320, BB4 = 352;
    constexpr int W5 = 384, B5 = 672, G5 = 675, BB5 = 678;
    constexpr int W6 = 681, B6 = 690, G6 = 691, BB6 = 692, NW = 693;
    __shared__ float s_w[NW];
    __shared__ float s_com[3][512];
    __shared__ float s_y[32][512];
    __shared__ float s_stat[32][2];
    const int tid = threadIdx.x, lane = tid & 63, wid = tid >> 6, l = tid;

    if (tid < 288) s_w[W4 + tid] = w4[tid];
    if (tid < 32) { s_w[B4 + tid] = b4[tid]; s_w[G4 + tid] = g4[tid]; s_w[BB4 + tid] = bb4[tid]; }
    if (tid < 288) s_w[W5 + tid] = w5[tid];
    if (tid < 3) { s_w[B5 + tid] = b5[tid]; s_w[G5 + tid] = g5[tid]; s_w[BB5 + tid] = bb5[tid]; }
    if (tid < 9) s_w[W6 + tid] = w6[tid];
    if (tid == 0) { s_w[B6] = b6[0]; s_w[G6] = g6[0]; s_w[BB6] = bb6[0]; }

    float den = 0.f;
#pragma unroll 8
    for (int i = 0; i < 128; ++i) den += ws[WSF_ADEN + i];
    const float invS = 1.0f / den;
    float a0 = 0.f, a1 = 0.f;
#pragma unroll 8
    for (int p = 0; p < 128; ++p) {
        a0 += ws[WSF_APART + p*1024 + l];
        a1 += ws[WSF_APART + p*1024 + 512 + l];
    }
    const int x = xidx[0];
    s_com[0][l] = a0 * invS;
    s_com[1][l] = a1 * invS;
    s_com[2][l] = emb[(size_t)x*512 + l];
    __syncthreads();

    // ---- conv4 (3->32) ----
    float px[3][3];
#pragma unroll
    for (int ic = 0; ic < 3; ++ic) {
        px[ic][0] = (l > 0)   ? s_com[ic][l-1] : 0.f;
        px[ic][1] =             s_com[ic][l];
        px[ic][2] = (l < 511) ? s_com[ic][l+1] : 0.f;
    }
#pragma unroll 4
    for (int oc = 0; oc < 32; ++oc) {
        float a = s_w[B4 + oc];
#pragma unroll
        for (int ic = 0; ic < 3; ++ic)
#pragma unroll
            for (int k = 0; k < 3; ++k)
                a += s_w[W4 + oc*9 + ic*3 + k] * px[ic][k];
        s_y[oc][l] = a;
    }
    __syncthreads();
#pragma unroll
    for (int t = 0; t < 4; ++t) {
        const int oc = wid * 4 + t;
        float s = 0.f, s2 = 0.f;
#pragma unroll
        for (int j = 0; j < 8; ++j) { float v = s_y[oc][lane + j*64]; s += v; s2 += v*v; }
        s = wave_rsum(s); s2 = wave_rsum(s2);
        if (lane == 0) { float m = s/512.f, var = s2/512.f - m*m; s_stat[oc][0] = m; s_stat[oc][1] = rsqrtf(var + 1e-5f); }
    }
    __syncthreads();
#pragma unroll 4
    for (int oc = 0; oc < 32; ++oc)
        s_y[oc][l] = fmaxf((s_y[oc][l] - s_stat[oc][0]) * s_stat[oc][1] * s_w[G4+oc] + s_w[BB4+oc], 0.f);
    __syncthreads();

    // ---- conv5 (32->3) + residual ----
    float y2[3];
#pragma unroll
    for (int oc = 0; oc < 3; ++oc) y2[oc] = s_w[B5 + oc];
#pragma unroll 2
    for (int ic = 0; ic < 32; ++ic) {
        float c0 = (l > 0)   ? s_y[ic][l-1] : 0.f;
        float c1 =             s_y[ic][l];
        float c2 = (l < 511) ? s_y[ic][l+1] : 0.f;
#pragma unroll
        for (int oc = 0; oc < 3; ++oc) {
            const int base = W5 + (oc*32 + ic)*3;
            y2[oc] += s_w[base]*c0 + s_w[base+1]*c1 + s_w[base+2]*c2;
        }
    }
#pragma unroll
    for (int oc = 0; oc < 3; ++oc) y2[oc] += s_com[oc][l];
    __syncthreads();
#pragma unroll
    for (int oc = 0; oc < 3; ++oc) s_y[oc][l] = y2[oc];
    __syncthreads();
    if (wid < 3) {
        const int oc = wid;
        float s = 0.f, s2 = 0.f;
#pragma unroll
        for (int j = 0; j < 8; ++j) { float v = s_y[oc][lane + j*64]; s += v; s2 += v*v; }
        s = wave_rsum(s); s2 = wave_rsum(s2);
        if (lane == 0) { float m = s/512.f, var = s2/512.f - m*m; s_stat[oc][0] = m; s_stat[oc][1] = rsqrtf(var + 1e-5f); }
    }
    __syncthreads();
#pragma unroll
    for (int oc = 0; oc < 3; ++oc)
        s_com[oc][l] = fmaxf((y2[oc] - s_stat[oc][0]) * s_stat[oc][1] * s_w[G5+oc] + s_w[BB5+oc], 0.f);
    __syncthreads();

    // ---- conv6 (3->1) ----
    float a6 = s_w[B6];
#pragma unroll
    for (int ic = 0; ic < 3; ++ic) {
        float c0 = (l > 0)   ? s_com[ic][l-1] : 0.f;
        float c1 =             s_com[ic][l];
        float c2 = (l < 511) ? s_com[ic][l+1] : 0.f;
        a6 += s_w[W6+ic*3]*c0 + s_w[W6+ic*3+1]*c1 + s_w[W6+ic*3+2]*c2;
    }
    s_y[0][l] = a6;
    __syncthreads();
    if (wid == 0) {
        float s = 0.f, s2 = 0.f;
#pragma unroll
        for (int j = 0; j < 8; ++j) { float v = s_y[0][lane + j*64]; s += v; s2 += v*v; }
        s = wave_rsum(s); s2 = wave_rsum(s2);
        if (lane == 0) { float m = s/512.f, var = s2/512.f - m*m; s_stat[0][0] = m; s_stat[0][1] = rsqrtf(var + 1e-5f); }
    }
    __syncthreads();
    ws[WSF_XT + l] = fmaxf((a6 - s_stat[0][0]) * s_stat[0][1] * s_w[G6] + s_w[BB6], 0.f);
}

// =====================================================================
// K4: one GRU layer, WIDENED to 256 blocks x 256.  Block owns 2 units;
// wave w: unit (w>>1), matrix wih (w even) / whh (w odd), 3 gate rows.
// Same math as R6's k_gru (raw dots in s_g, biases in the final thread).
// =====================================================================
__global__ __launch_bounds__(256) void k_gru(
    const float* __restrict__ wih, const float* __restrict__ whh,
    const float* __restrict__ bih, const float* __restrict__ bhh,
    const float* __restrict__ hstate,
    const float* __restrict__ xt_in, float* __restrict__ xt_out,
    float* __restrict__ hout, int layer)
{
    wih += (size_t)layer * 1536 * 512;
    whh += (size_t)layer * 1536 * 512;
    bih += layer * 1536;
    bhh += layer * 1536;
    const float* hp = hstate + layer * 512;

    const int tid = threadIdx.x, lane = tid & 63, wid = tid >> 6;
    const int i0 = blockIdx.x * 2;
    const int lu = wid >> 1;            // local unit 0/1
    const int useH = wid & 1;           // 0: wih/xt, 1: whh/h
    const int u = i0 + lu;

    const float* vsrc = useH ? hp : xt_in;
    const float* wmat = useH ? whh : wih;
    float v0[4], v1[4];
#pragma unroll
    for (int j = 0; j < 4; ++j) {
        v0[j] = vsrc[lane*4 + j];
        v1[j] = vsrc[256 + lane*4 + j];
    }
    __shared__ float s_g[2][6];
#pragma unroll
    for (int g = 0; g < 3; ++g) {
        const float* wr = wmat + (size_t)(u + g*512) * 512;
        f32x4 w0 = *(const f32x4*)(wr + lane*4);
        f32x4 w1 = *(const f32x4*)(wr + 256 + lane*4);
        float a = 0.f;
#pragma unroll
        for (int j = 0; j < 4; ++j) a += w0[j]*v0[j] + w1[j]*v1[j];
        a = wave_rsum(a);
        if (lane == 0) s_g[lu][useH*3 + g] = a;
    }
    __syncthreads();
    if (tid < 2) {
        const int i = i0 + tid;
        float ir = s_g[tid][0] + bih[i];
        float iz = s_g[tid][1] + bih[i + 512];
        float in_ = s_g[tid][2] + bih[i + 1024];
        float hr = s_g[tid][3] + bhh[i];
        float hz = s_g[tid][4] + bhh[i + 512];
        float hn = s_g[tid][5] + bhh[i + 1024];
        float r = sigm(ir + hr);
        float z = sigm(iz + hz);
        float n = tanhf(in_ + r * hn);
        float h = (1.f - z) * n + z * hp[i];
        xt_out[i] = h;
        hout[i] = h;
    }
}

// =====================================================================
// K5: vocab GEMV + per-block online (max, sum-exp).  786 x 256 (R6 exact)
// =====================================================================
__global__ __launch_bounds__(256) void k_vocab(
    const float* __restrict__ low, const float* __restrict__ lob,
    float* __restrict__ ws)
{
    const int tid = threadIdx.x, lane = tid & 63, wid = tid >> 6;
    float q0[4], q1[4];
#pragma unroll
    for (int j = 0; j < 4; ++j) {
        q0[j] = ws[WSF_XT + 4*512 + lane*4 + j];
        q1[j] = ws[WSF_XT + 4*512 + 256 + lane*4 + j];
    }
    const int row0 = blockIdx.x * 64 + wid * 16;
    float m = -INFINITY, s = 0.0f;
#pragma unroll 4
    for (int r = 0; r < 16; ++r) {
        const int row = row0 + r;
        if (row < NVOCAB) {
            f32x4 w0 = *(const f32x4*)(low + (size_t)row*512 + lane*4);
            f32x4 w1 = *(const f32x4*)(low + (size_t)row*512 + 256 + lane*4);
            float a = 0.f;
#pragma unroll
            for (int j = 0; j < 4; ++j) a += w0[j]*q0[j] + w1[j]*q1[j];
            a = wave_rsum(a);
            if (lane == 0) {
                float v = a + lob[row];
                ws[WSF_LOGV + row] = v;
                if (v > m) { s = s * __expf(m - v) + 1.0f; m = v; }
                else       { s += __expf(v - m); }
            }
        }
    }
    __shared__ float smx[4], ssx[4];
    if (lane == 0) { smx[wid] = m; ssx[wid] = s; }
    __syncthreads();
    if (tid == 0) {
        float M = -INFINITY, S = 0.0f;
#pragma unroll
        for (int w = 0; w < 4; ++w) {
            float mb = smx[w], sb = ssx[w];
            if (sb > 0.0f) {
                if (mb > M) { S = S * __expf(M - mb) + sb; M = mb; }
                else        { S += sb * __expf(mb - M); }
            }
        }
        ws[WSF_PM + blockIdx.x] = M;
        ws[WSF_PS + blockIdx.x] = S;
    }
}

// =====================================================================
// K6: redundant deterministic LSE + write log-probs.  197 blocks x 256
// =====================================================================
__global__ __launch_bounds__(256) void k_outlse(
    const float* __restrict__ ws, float* __restrict__ out)
{
    __shared__ float smx[256], ssx[256];
    const int tid = threadIdx.x;
    float M = -INFINITY, S = 0.0f;
    for (int i = tid; i < NBLK_V; i += 256) {
        float mb = ws[WSF_PM + i], sb = ws[WSF_PS + i];
        if (mb > M) { S = S * __expf(M - mb) + sb; M = mb; }
        else        { S += sb * __expf(mb - M); }
    }
    smx[tid] = M; ssx[tid] = S;
    __syncthreads();
    for (int st = 128; st > 0; st >>= 1) {
        if (tid < st) {
            float mb = smx[tid + st], sb = ssx[tid + st];
            if (sb > 0.0f) {
                if (mb > smx[tid]) { ssx[tid] = ssx[tid] * __expf(smx[tid] - mb) + sb; smx[tid] = mb; }
                else               { ssx[tid] += sb * __expf(mb - smx[tid]); }
            }
        }
        __syncthreads();
    }
    const float lse = smx[0] + logf(ssx[0]);
    const int i = blockIdx.x * 256 + tid;
    if (i < NVOCAB) out[i] = ws[WSF_LOGV + i] - lse;
}

// =====================================================================
extern "C" void kernel_launch(void* const* d_in, const int* in_sizes, int n_in,
                              void* d_out, int out_size, void* d_ws, size_t ws_size,
                              hipStream_t stream)
{
    (void)in_sizes; (void)n_in; (void)out_size; (void)ws_size;
    const float* emb     = (const float*)d_in[0];
    const float* conv1_w = (const float*)d_in[1];  const float* conv1_b = (const float*)d_in[2];
    const float* conv2_w = (const float*)d_in[3];  const float* conv2_b = (const float*)d_in[4];
    const float* conv3_w = (const float*)d_in[5];  const float* conv3_b = (const float*)d_in[6];
    const float* conv4_w = (const float*)d_in[7];  const float* conv4_b = (const float*)d_in[8];
    const float* conv5_w = (const float*)d_in[9];  const float* conv5_b = (const float*)d_in[10];
    const float* conv6_w = (const float*)d_in[11]; const float* conv6_b = (const float*)d_in[12];
    const float* bn1_g = (const float*)d_in[13];   const float* bn1_b = (const float*)d_in[14];
    const float* bn2_g = (const float*)d_in[15];   const float* bn2_b = (const float*)d_in[16];
    const float* bn3_g = (const float*)d_in[17];   const float* bn3_b = (const float*)d_in[18];
    const float* bn4_g = (const float*)d_in[19];   const float* bn4_b = (const float*)d_in[20];
    const float* bn5_g = (const float*)d_in[21];   const float* bn5_b = (const float*)d_in[22];
    const float* bn6_g = (const float*)d_in[23];   const float* bn6_b = (const float*)d_in[24];
    const float* att_w = (const float*)d_in[25];   const float* att_b = (const float*)d_in[26];
    const float* gru_wih = (const float*)d_in[27]; const float* gru_whh = (const float*)d_in[28];
    const float* gru_bih = (const float*)d_in[29]; const float* gru_bhh = (const float*)d_in[30];
    const float* lo_w = (const float*)d_in[31];    const float* lo_b = (const float*)d_in[32];
    const float* h_state = (const float*)d_in[33];
    const float* enc = (const float*)d_in[34];
    const int* x = (const int*)d_in[35];

    float* ws = (float*)d_ws;
    float* out = (float*)d_out;

    k_pre<<<1, 512, 0, stream>>>(emb, x, h_state,
        conv1_w, conv1_b, conv2_w, conv2_b, conv3_w, conv3_b,
        bn1_g, bn1_b, bn2_g, bn2_b, bn3_g, bn3_b, ws);
    k_att<<<128, 256, 0, stream>>>(att_w, att_b, enc, ws);
    k_post<<<1, 512, 0, stream>>>(emb, x,
        conv4_w, conv4_b, conv5_w, conv5_b, conv6_w, conv6_b,
        bn4_g, bn4_b, bn5_g, bn5_b, bn6_g, bn6_b, ws);
    for (int l = 0; l < 4; ++l) {
        k_gru<<<256, 256, 0, stream>>>(gru_wih, gru_whh, gru_bih, gru_bhh, h_state,
            ws + WSF_XT + l * 512, ws + WSF_XT + (l + 1) * 512,
            out + NVOCAB + l * 512, l);
    }
    k_vocab<<<NBLK_V, 256, 0, stream>>>(lo_w, lo_b, ws);
    k_outlse<<<197, 256, 0, stream>>>(ws, out);
}